// Round 6
// baseline (1087.913 us; speedup 1.0000x reference)
//
#include <hip/hip_runtime.h>

// CfC, round 6: scan/proj split (R5) + overlap & stall fixes.
//  - barriers drain lgkmcnt only (no vmcnt store-drain per step)
//  - phase B interleaved: af(sub0) chains -> blend sub0 -> af(sub1) -> blend sub1
//  - x pre-converted to fp16 (x2h kernel, ws-gated); seq stored in phase A as
//    masked b128 stores from ha fragments
//  K1 cfc_scan2<XH>: 16 blocks x 512 thr. K2 cfc_proj unchanged.
//  Fallbacks: ws >= 84MB: full path; >= 67MB: f32-x scan; else fused R3.

#define T_   512
#define IND  64
#define LAT  256
#define BBD  128
#define OUTD 64
#define HLF  128

typedef _Float16 half8 __attribute__((ext_vector_type(8)));
typedef float    f32x4 __attribute__((ext_vector_type(4)));
typedef float    f4    __attribute__((ext_vector_type(4)));

#define MFMA16(a,b,c) __builtin_amdgcn_mfma_f32_16x16x32_f16((a),(b),(c),0,0,0)

__device__ __forceinline__ float ex2(float x)   { return __builtin_amdgcn_exp2f(x); }
__device__ __forceinline__ float rcpf_(float x) { return __builtin_amdgcn_rcpf(x); }
// LDS-only barrier: ds-writes visible, global stores NOT drained.
__device__ __forceinline__ void barrier_lds() {
    asm volatile("s_waitcnt lgkmcnt(0)\n\ts_barrier" ::: "memory");
}

// ====================== K0: x -> fp16 pre-convert ===========================
__global__ void __launch_bounds__(256) x2h(const float* __restrict__ x,
                                           _Float16* __restrict__ xh) {
    const size_t i = ((size_t)blockIdx.x * 256 + threadIdx.x) * 16;
    f4 a = *(const f4*)(x + i);
    f4 b = *(const f4*)(x + i + 4);
    f4 c = *(const f4*)(x + i + 8);
    f4 d = *(const f4*)(x + i + 12);
    half8 lo, hi;
    #pragma unroll
    for (int e = 0; e < 4; ++e) {
        lo[e] = (_Float16)a[e]; lo[e+4] = (_Float16)b[e];
        hi[e] = (_Float16)c[e]; hi[e+4] = (_Float16)d[e];
    }
    *(half8*)(xh + i)     = lo;
    *(half8*)(xh + i + 8) = hi;
}

// ============================ K1: recurrence scan ============================
template<bool XH>
__global__ void __launch_bounds__(512, 2) cfc_scan2(
    const float* __restrict__ x, const _Float16* __restrict__ xh,
    const float* __restrict__ Wb,  const float* __restrict__ bb,
    const float* __restrict__ W1,  const float* __restrict__ b1,
    const float* __restrict__ W2,  const float* __restrict__ b2,
    const float* __restrict__ Wa,  const float* __restrict__ ba,
    const float* __restrict__ Wtb, const float* __restrict__ btb,
    _Float16* __restrict__ seq)
{
    const int tid  = threadIdx.x;
    const int wv   = tid >> 6;
    const int lane = tid & 63;
    const int l15  = lane & 15;
    const int lg   = lane >> 4;
    const int krow = lg << 3;
    const int b0   = blockIdx.x << 4;

    __shared__ __align__(16) _Float16 hbuf[16*LAT];   // 8KB
    __shared__ __align__(16) _Float16 zbuf[16*BBD];   // 4KB

    half8 WbB[10];
    {
        const int col = (wv<<4) + l15;
        #pragma unroll
        for (int kk = 0; kk < 10; ++kk) {
            half8 v;
            #pragma unroll
            for (int e = 0; e < 8; ++e)
                v[e] = (_Float16)Wb[(kk*32 + krow + e)*BBD + col];
            WbB[kk] = v;
        }
    }
    half8 WfB[6][4];   // 0,1=W1 2,3=W2 4,5=Wa+Wtb ; 1.7159 folded
    #pragma unroll
    for (int t6 = 0; t6 < 6; ++t6) {
        const int m   = t6 >> 1;
        const int col = (wv<<5) + ((t6&1)<<4) + l15;
        const float* Wm = (m==0) ? W1 : ((m==1) ? W2 : Wa);
        #pragma unroll
        for (int kk = 0; kk < 4; ++kk) {
            half8 v;
            #pragma unroll
            for (int e = 0; e < 8; ++e) {
                const int k = kk*32 + krow + e;
                float f = Wm[k*LAT + col];
                if (m == 2) f += Wtb[k*LAT + col];
                v[e] = (_Float16)(1.7159f * f);
            }
            WfB[t6][kk] = v;
        }
    }

    const float K1 = 1.4426950408889634f;
    const float K2 = 2.8853900817779268f;
    const float KZ = 1.9216698144680396f;
    const int cz  = (wv<<4) + l15;
    const int cf0 = (wv<<5) + l15;
    const int cf1 = cf0 + 16;
    const float bbr   = bb[cz] * KZ;
    const float b1r0  = b1[cf0]*K2,  b1r1  = b1[cf1]*K2;
    const float b2r0  = b2[cf0]*K2,  b2r1  = b2[cf1]*K2;
    const float batr0 = (ba[cf0]+btb[cf0])*K1, batr1 = (ba[cf1]+btb[cf1])*K1;

    // x pointers / prefetch
    const float*    xrow  = x  + (size_t)(b0 + l15) * (T_*IND);
    const _Float16* xhrow = xh + (size_t)(b0 + l15) * (T_*IND);
    f4 xq[4];
    half8 xn0, xn1;
    if (XH) {
        xn0 = *(const half8*)(xhrow + krow);
        xn1 = *(const half8*)(xhrow + 32 + krow);
    } else {
        #pragma unroll
        for (int q = 0; q < 4; ++q)
            xq[q] = *(const f4*)(xrow + ((q>>1)*32 + krow + (q&1)*4));
    }

    half8 ha[8];
    {
        half8 hz;
        #pragma unroll
        for (int e = 0; e < 8; ++e) hz[e] = (_Float16)0.f;
        #pragma unroll
        for (int i = 0; i < 8; ++i) ha[i] = hz;
    }
    const f32x4 fz = {0.f, 0.f, 0.f, 0.f};

    // seq store base for masked-lane bulk stores (rows 2wv, 2wv+1)
    const bool smask = ((l15 >> 1) == wv);
    _Float16* const sqrow = seq + ((size_t)(b0 + l15) * T_) * LAT + krow;

    #pragma unroll 1
    for (int t = 0; t < T_; ++t) {
        // ============================ PHASE A ============================
        if (t > 0) {
            #pragma unroll
            for (int kk = 0; kk < 8; ++kk)
                ha[kk] = *(const half8*)&hbuf[(l15*LAT + kk*32 + krow) ^ ((l15&7)<<3)];
            // bulk seq store of h(t-1) from ha fragments (8 lanes per wave)
            if (smask) {
                _Float16* sp = sqrow + (size_t)(t-1) * LAT;
                #pragma unroll
                for (int kk = 0; kk < 8; ++kk)
                    *(half8*)(sp + kk*32) = ha[kk];
            }
        }

        // current x fragments + prefetch next
        half8 xa0, xa1;
        if (XH) {
            xa0 = xn0; xa1 = xn1;
            const int tn = (t < T_-1) ? (t+1) : t;
            xn0 = *(const half8*)(xhrow + tn*IND + krow);
            xn1 = *(const half8*)(xhrow + tn*IND + 32 + krow);
        } else {
            #pragma unroll
            for (int e = 0; e < 4; ++e) {
                xa0[e]   = (_Float16)xq[0][e];
                xa0[e+4] = (_Float16)xq[1][e];
                xa1[e]   = (_Float16)xq[2][e];
                xa1[e+4] = (_Float16)xq[3][e];
            }
            const int tn = (t < T_-1) ? (t+1) : t;
            const float* p = xrow + tn*IND + krow;
            #pragma unroll
            for (int q = 0; q < 4; ++q)
                xq[q] = *(const f4*)(p + (q>>1)*32 + (q&1)*4);
        }

        // GEMM_h: 3 parallel chains
        f32x4 azx = MFMA16(xa0, WbB[0], fz);
        azx = MFMA16(xa1, WbB[1], azx);
        f32x4 az0 = MFMA16(ha[0], WbB[2], fz);
        f32x4 az1 = MFMA16(ha[1], WbB[3], fz);
        #pragma unroll
        for (int kk = 2; kk < 8; kk += 2) {
            az0 = MFMA16(ha[kk],   WbB[kk+2], az0);
            az1 = MFMA16(ha[kk+1], WbB[kk+3], az1);
        }
        const f32x4 az = (azx + az0) + az1;

        #pragma unroll
        for (int r = 0; r < 4; ++r) {
            const float E = ex2(__builtin_fmaf(az[r], KZ, bbr));
            const float z = __builtin_fmaf(-2.f, rcpf_(E + 1.f), 1.f);
            const int row = (lg<<2) + r;
            zbuf[(row*BBD + cz) ^ ((row&7)<<3)] = (_Float16)z;
        }
        barrier_lds();   // bar 1: zbuf ready

        // ============================ PHASE B ============================
        half8 za[4];
        #pragma unroll
        for (int kk = 0; kk < 4; ++kk)
            za[kk] = *(const half8*)&zbuf[(l15*BBD + kk*32 + krow) ^ ((l15&7)<<3)];

        // ---- sub0: tiles 0,2,4 ----
        f32x4 af0 = fz, af2 = fz, af4 = fz;
        #pragma unroll
        for (int kk = 0; kk < 4; ++kk) {
            af0 = MFMA16(za[kk], WfB[0][kk], af0);
            af2 = MFMA16(za[kk], WfB[2][kk], af2);
            af4 = MFMA16(za[kk], WfB[4][kk], af4);
        }
        #pragma unroll
        for (int r = 0; r < 4; ++r) {
            const float E1 = ex2(__builtin_fmaf(af0[r], K2, b1r0));
            const float E2 = ex2(__builtin_fmaf(af2[r], K2, b2r0));
            const float E3 = ex2(__builtin_fmaf(af4[r], K1, batr0));
            const float p1_ = E1 + 1.f;
            const float p2_ = E2 + 1.f;
            const float p3_ = E3 + 1.f;
            const float num = __builtin_fmaf(E3, p1_, p2_);
            const float hv  = __builtin_fmaf(-2.f*num, rcpf_(p1_*p2_*p3_), 1.f);
            const int row = (lg<<2) + r;
            hbuf[(row*LAT + (wv<<5) + l15) ^ ((row&7)<<3)] = (_Float16)hv;
        }

        // ---- sub1: tiles 1,3,5 (MFMAs overlap sub0's transcendentals) ----
        f32x4 af1 = fz, af3 = fz, af5 = fz;
        #pragma unroll
        for (int kk = 0; kk < 4; ++kk) {
            af1 = MFMA16(za[kk], WfB[1][kk], af1);
            af3 = MFMA16(za[kk], WfB[3][kk], af3);
            af5 = MFMA16(za[kk], WfB[5][kk], af5);
        }
        #pragma unroll
        for (int r = 0; r < 4; ++r) {
            const float E1 = ex2(__builtin_fmaf(af1[r], K2, b1r1));
            const float E2 = ex2(__builtin_fmaf(af3[r], K2, b2r1));
            const float E3 = ex2(__builtin_fmaf(af5[r], K1, batr1));
            const float p1_ = E1 + 1.f;
            const float p2_ = E2 + 1.f;
            const float p3_ = E3 + 1.f;
            const float num = __builtin_fmaf(E3, p1_, p2_);
            const float hv  = __builtin_fmaf(-2.f*num, rcpf_(p1_*p2_*p3_), 1.f);
            const int row = (lg<<2) + r;
            hbuf[(row*LAT + (wv<<5) + 16 + l15) ^ ((row&7)<<3)] = (_Float16)hv;
        }
        barrier_lds();   // bar 2: hbuf ready for t+1
    }

    // epilogue: store seq(T-1) from hbuf
    if (smask) {
        _Float16* sp = sqrow + (size_t)(T_-1) * LAT;
        #pragma unroll
        for (int kk = 0; kk < 8; ++kk) {
            const half8 hv = *(const half8*)&hbuf[(l15*LAT + kk*32 + krow) ^ ((l15&7)<<3)];
            *(half8*)(sp + kk*32) = hv;
        }
    }
}

// ============================ K2: projection =================================
__global__ void __launch_bounds__(256, 2) cfc_proj(
    const _Float16* __restrict__ seq,
    const float* __restrict__ Wp1, const float* __restrict__ bp1,
    const float* __restrict__ Wp2, const float* __restrict__ bp2,
    float* __restrict__ out)
{
    const int tid  = threadIdx.x;
    const int wv   = tid >> 6;      // 0..3
    const int lane = tid & 63;
    const int l15  = lane & 15;
    const int lg   = lane >> 4;
    const int krow = lg << 3;

    __shared__ __align__(16) _Float16 wp1l[64*512];      // 64KB
    __shared__ __align__(16) _Float16 wp2l[16*512];      // 16KB
    __shared__ __align__(16) _Float16 dbuf[4][16*HLF];   // 16KB

    #pragma unroll
    for (int f = 0; f < 16; ++f) {
        const int g = wv*16 + f, tt = g >> 3, kk = g & 7;
        half8 v;
        #pragma unroll
        for (int e = 0; e < 8; ++e)
            v[e] = (_Float16)Wp1[(kk*32 + krow + e)*HLF + (tt<<4) + l15];
        *(half8*)&wp1l[g*512 + (lane<<3)] = v;
    }
    #pragma unroll
    for (int f = 0; f < 4; ++f) {
        const int g = wv*4 + f, tt = g >> 2, kk = g & 3;
        half8 v;
        #pragma unroll
        for (int e = 0; e < 8; ++e)
            v[e] = (_Float16)Wp2[(kk*32 + krow + e)*OUTD + (tt<<4) + l15];
        *(half8*)&wp2l[g*512 + (lane<<3)] = v;
    }

    const float K1 = 1.4426950408889634f;
    float bp1v[8], bp1kv[8];
    #pragma unroll
    for (int tt = 0; tt < 8; ++tt) {
        bp1v[tt]  = bp1[(tt<<4) + l15];
        bp1kv[tt] = bp1v[tt] * K1;
    }
    float bp2v[4];
    #pragma unroll
    for (int tt = 0; tt < 4; ++tt) bp2v[tt] = bp2[(tt<<4) + l15];

    __syncthreads();

    const int m0 = (blockIdx.x*4 + wv) << 4;
    const f32x4 fz = {0.f, 0.f, 0.f, 0.f};

    half8 ha[8];
    {
        const _Float16* ap = seq + (size_t)(m0 + l15)*LAT + krow;
        #pragma unroll
        for (int kk = 0; kk < 8; ++kk)
            ha[kk] = *(const half8*)(ap + kk*32);
    }

    #pragma unroll
    for (int tt = 0; tt < 8; ++tt) {
        f32x4 a0 = fz, a1 = fz;
        #pragma unroll
        for (int kk = 0; kk < 8; kk += 2) {
            a0 = MFMA16(ha[kk],   *(const half8*)&wp1l[((tt<<3)+kk  )*512 + (lane<<3)], a0);
            a1 = MFMA16(ha[kk+1], *(const half8*)&wp1l[((tt<<3)+kk+1)*512 + (lane<<3)], a1);
        }
        const f32x4 ap = a0 + a1;
        #pragma unroll
        for (int r = 0; r < 4; ++r) {
            const float v  = ap[r] + bp1v[tt];
            const float E  = ex2(__builtin_fmaf(ap[r], K1, bp1kv[tt]));
            const float sg = rcpf_(E + 1.f);
            const float hd = __builtin_fmaf(-v, sg, v);
            const int row = (lg<<2) + r;
            dbuf[wv][(row*HLF + (tt<<4) + l15) ^ ((row&7)<<3)] = (_Float16)hd;
        }
    }

    half8 pa[4];
    #pragma unroll
    for (int kk = 0; kk < 4; ++kk)
        pa[kk] = *(const half8*)&dbuf[wv][(l15*HLF + kk*32 + krow) ^ ((l15&7)<<3)];
    #pragma unroll
    for (int tt = 0; tt < 4; ++tt) {
        f32x4 ao = fz;
        #pragma unroll
        for (int kk = 0; kk < 4; ++kk)
            ao = MFMA16(pa[kk], *(const half8*)&wp2l[((tt<<2)+kk)*512 + (lane<<3)], ao);
        #pragma unroll
        for (int r = 0; r < 4; ++r)
            out[(size_t)(m0 + (lg<<2) + r)*OUTD + (tt<<4) + l15] = ao[r] + bp2v[tt];
    }
}

// ==================== fallback: R3 fused kernel (ws too small) ===============
__global__ void __launch_bounds__(512, 2) cfc_fused_fb(
    const float* __restrict__ x,
    const float* __restrict__ Wb,  const float* __restrict__ bb,
    const float* __restrict__ W1,  const float* __restrict__ b1,
    const float* __restrict__ W2,  const float* __restrict__ b2,
    const float* __restrict__ Wa,  const float* __restrict__ ba,
    const float* __restrict__ Wtb, const float* __restrict__ btb,
    const float* __restrict__ Wp1, const float* __restrict__ bp1,
    const float* __restrict__ Wp2, const float* __restrict__ bp2,
    float* __restrict__ out)
{
    const int tid  = threadIdx.x;
    const int wv   = tid >> 6;
    const int lane = tid & 63;
    const int l15  = lane & 15;
    const int lg   = lane >> 4;
    const int krow = lg << 3;
    const int b0   = blockIdx.x << 4;

    __shared__ __align__(16) _Float16 hbuf[16*LAT];
    __shared__ __align__(16) _Float16 zbuf[16*BBD];
    __shared__ __align__(16) _Float16 dbuf[16*HLF];
    __shared__ __align__(16) _Float16 wp1l[64*512];
    __shared__ __align__(16) _Float16 wp2l[16*512];

    half8 WbB[10];
    {
        const int col = (wv<<4) + l15;
        #pragma unroll
        for (int kk = 0; kk < 10; ++kk) {
            half8 v;
            #pragma unroll
            for (int e = 0; e < 8; ++e)
                v[e] = (_Float16)Wb[(kk*32 + krow + e)*BBD + col];
            WbB[kk] = v;
        }
    }
    half8 WfB[6][4];
    #pragma unroll
    for (int t6 = 0; t6 < 6; ++t6) {
        const int m   = t6 >> 1;
        const int col = (wv<<5) + ((t6&1)<<4) + l15;
        const float* Wm = (m==0) ? W1 : ((m==1) ? W2 : Wa);
        #pragma unroll
        for (int kk = 0; kk < 4; ++kk) {
            half8 v;
            #pragma unroll
            for (int e = 0; e < 8; ++e) {
                const int k = kk*32 + krow + e;
                float f = Wm[k*LAT + col];
                if (m == 2) f += Wtb[k*LAT + col];
                v[e] = (_Float16)(1.7159f * f);
            }
            WfB[t6][kk] = v;
        }
    }
    {
        const int col = (wv<<4) + l15;
        #pragma unroll
        for (int kk = 0; kk < 8; ++kk) {
            half8 v;
            #pragma unroll
            for (int e = 0; e < 8; ++e)
                v[e] = (_Float16)Wp1[(kk*32 + krow + e)*HLF + col];
            *(half8*)&wp1l[((wv<<3) + kk)*512 + (lane<<3)] = v;
        }
        if (wv < 4) {
            #pragma unroll
            for (int kk = 0; kk < 4; ++kk) {
                half8 v;
                #pragma unroll
                for (int e = 0; e < 8; ++e)
                    v[e] = (_Float16)Wp2[(kk*32 + krow + e)*OUTD + col];
                *(half8*)&wp2l[((wv<<2) + kk)*512 + (lane<<3)] = v;
            }
        }
    }
    const _Float16* const wp1p = &wp1l[(wv<<3)*512 + (lane<<3)];
    const _Float16* const wp2p = &wp2l[(wv<<2)*512 + (lane<<3)];

    const float K1 = 1.4426950408889634f;
    const float K2 = 2.8853900817779268f;
    const float KZ = 1.9216698144680396f;
    const int cz  = (wv<<4) + l15;
    const int cf0 = (wv<<5) + l15;
    const int cf1 = cf0 + 16;
    const float bbr   = bb[cz] * KZ;
    const float b1r0  = b1[cf0]*K2,  b1r1  = b1[cf1]*K2;
    const float b2r0  = b2[cf0]*K2,  b2r1  = b2[cf1]*K2;
    const float batr0 = (ba[cf0]+btb[cf0])*K1, batr1 = (ba[cf1]+btb[cf1])*K1;
    const float bp1a  = bp1[cz];
    const float bp1k  = bp1a * K1;
    const float bp2r  = (wv < 4) ? bp2[cz] : 0.f;

    __syncthreads();

    const float* xrow = x + (size_t)(b0 + l15) * (T_*IND);
    f4 xq[4];
    #pragma unroll
    for (int q = 0; q < 4; ++q)
        xq[q] = *(const f4*)(xrow + ((q>>1)*32 + krow + (q&1)*4));

    half8 ha[8];
    {
        half8 hz;
        #pragma unroll
        for (int e = 0; e < 8; ++e) hz[e] = (_Float16)0.f;
        #pragma unroll
        for (int i = 0; i < 8; ++i) ha[i] = hz;
    }
    const f32x4 fz = {0.f, 0.f, 0.f, 0.f};
    float* const obase = out + (size_t)(b0 + (lg<<2)) * (T_*OUTD) + (wv<<4) + l15;

    #pragma unroll 1
    for (int t = 0; t < T_; ++t) {
        if (t > 0) {
            #pragma unroll
            for (int kk = 0; kk < 8; ++kk)
                ha[kk] = *(const half8*)&hbuf[(l15*LAT + kk*32 + krow) ^ ((l15&7)<<3)];
        }
        half8 xa0, xa1;
        #pragma unroll
        for (int e = 0; e < 4; ++e) {
            xa0[e]   = (_Float16)xq[0][e];
            xa0[e+4] = (_Float16)xq[1][e];
            xa1[e]   = (_Float16)xq[2][e];
            xa1[e+4] = (_Float16)xq[3][e];
        }
        {
            const int tn = (t < T_-1) ? (t+1) : t;
            const float* p = xrow + tn*IND + krow;
            #pragma unroll
            for (int q = 0; q < 4; ++q)
                xq[q] = *(const f4*)(p + (q>>1)*32 + (q&1)*4);
        }
        f32x4 az0 = MFMA16(xa0, WbB[0], fz);
        f32x4 az1 = MFMA16(xa1, WbB[1], fz);
        #pragma unroll
        for (int kk = 0; kk < 8; kk += 2) {
            az0 = MFMA16(ha[kk],   WbB[kk+2], az0);
            az1 = MFMA16(ha[kk+1], WbB[kk+3], az1);
        }
        const f32x4 az = az0 + az1;
        #pragma unroll
        for (int r = 0; r < 4; ++r) {
            const float E = ex2(__builtin_fmaf(az[r], KZ, bbr));
            const float z = __builtin_fmaf(-2.f, rcpf_(E + 1.f), 1.f);
            const int row = (lg<<2) + r;
            zbuf[(row*BBD + cz) ^ ((row&7)<<3)] = (_Float16)z;
        }
        if (t > 0) {
            f32x4 ap0 = fz, ap1 = fz;
            #pragma unroll
            for (int kk = 0; kk < 8; kk += 2) {
                ap0 = MFMA16(ha[kk],   *(const half8*)(wp1p +  kk   *512), ap0);
                ap1 = MFMA16(ha[kk+1], *(const half8*)(wp1p + (kk+1)*512), ap1);
            }
            const f32x4 ap = ap0 + ap1;
            #pragma unroll
            for (int r = 0; r < 4; ++r) {
                const float v  = ap[r] + bp1a;
                const float E  = ex2(__builtin_fmaf(ap[r], K1, bp1k));
                const float sg = rcpf_(E + 1.f);
                const float hd = __builtin_fmaf(-v, sg, v);
                const int row = (lg<<2) + r;
                dbuf[(row*HLF + cz) ^ ((row&7)<<3)] = (_Float16)hd;
            }
        }
        __syncthreads();

        half8 za[4];
        #pragma unroll
        for (int kk = 0; kk < 4; ++kk)
            za[kk] = *(const half8*)&zbuf[(l15*BBD + kk*32 + krow) ^ ((l15&7)<<3)];
        f32x4 af[6];
        #pragma unroll
        for (int i = 0; i < 6; ++i) af[i] = fz;
        #pragma unroll
        for (int kk = 0; kk < 4; ++kk) {
            #pragma unroll
            for (int i = 0; i < 6; ++i) af[i] = MFMA16(za[kk], WfB[i][kk], af[i]);
        }
        #pragma unroll
        for (int sub = 0; sub < 2; ++sub) {
            const float b1r  = sub ? b1r1  : b1r0;
            const float b2r  = sub ? b2r1  : b2r0;
            const float batr = sub ? batr1 : batr0;
            #pragma unroll
            for (int r = 0; r < 4; ++r) {
                const float E1 = ex2(__builtin_fmaf(af[0+sub][r], K2, b1r));
                const float E2 = ex2(__builtin_fmaf(af[2+sub][r], K2, b2r));
                const float E3 = ex2(__builtin_fmaf(af[4+sub][r], K1, batr));
                const float p1_ = E1 + 1.f;
                const float p2_ = E2 + 1.f;
                const float p3_ = E3 + 1.f;
                const float num = __builtin_fmaf(E3, p1_, p2_);
                const float hv  = __builtin_fmaf(-2.f*num, rcpf_(p1_*p2_*p3_), 1.f);
                const int row = (lg<<2) + r;
                hbuf[(row*LAT + (wv<<5) + (sub<<4) + l15) ^ ((row&7)<<3)] = (_Float16)hv;
            }
        }
        if (t > 0 && wv < 4) {
            f32x4 ao = fz;
            #pragma unroll
            for (int kk = 0; kk < 4; ++kk) {
                const half8 aa = *(const half8*)&dbuf[(l15*HLF + kk*32 + krow) ^ ((l15&7)<<3)];
                ao = MFMA16(aa, *(const half8*)(wp2p + kk*512), ao);
            }
            #pragma unroll
            for (int r = 0; r < 4; ++r)
                obase[(size_t)r*(T_*OUTD) + (size_t)(t-1)*OUTD] = ao[r] + bp2r;
        }
        __syncthreads();
    }
    {
        #pragma unroll
        for (int kk = 0; kk < 8; ++kk)
            ha[kk] = *(const half8*)&hbuf[(l15*LAT + kk*32 + krow) ^ ((l15&7)<<3)];
        f32x4 ap0 = fz, ap1 = fz;
        #pragma unroll
        for (int kk = 0; kk < 8; kk += 2) {
            ap0 = MFMA16(ha[kk],   *(const half8*)(wp1p +  kk   *512), ap0);
            ap1 = MFMA16(ha[kk+1], *(const half8*)(wp1p + (kk+1)*512), ap1);
        }
        const f32x4 ap = ap0 + ap1;
        #pragma unroll
        for (int r = 0; r < 4; ++r) {
            const float v  = ap[r] + bp1a;
            const float E  = ex2(__builtin_fmaf(ap[r], K1, bp1k));
            const float sg = rcpf_(E + 1.f);
            const float hd = __builtin_fmaf(-v, sg, v);
            const int row = (lg<<2) + r;
            dbuf[(row*HLF + cz) ^ ((row&7)<<3)] = (_Float16)hd;
        }
        __syncthreads();
        if (wv < 4) {
            f32x4 ao = fz;
            #pragma unroll
            for (int kk = 0; kk < 4; ++kk) {
                const half8 aa = *(const half8*)&dbuf[(l15*HLF + kk*32 + krow) ^ ((l15&7)<<3)];
                ao = MFMA16(aa, *(const half8*)(wp2p + kk*512), ao);
            }
            #pragma unroll
            for (int r = 0; r < 4; ++r)
                obase[(size_t)r*(T_*OUTD) + (size_t)(T_-1)*OUTD] = ao[r] + bp2r;
        }
    }
}

extern "C" void kernel_launch(void* const* d_in, const int* in_sizes, int n_in,
                              void* d_out, int out_size, void* d_ws, size_t ws_size,
                              hipStream_t stream) {
    (void)in_sizes; (void)n_in; (void)out_size;
    const float* x   = (const float*)d_in[0];
    const float* Wb  = (const float*)d_in[1];
    const float* bb  = (const float*)d_in[2];
    const float* W1  = (const float*)d_in[3];
    const float* b1  = (const float*)d_in[4];
    const float* W2  = (const float*)d_in[5];
    const float* b2  = (const float*)d_in[6];
    const float* Wa  = (const float*)d_in[7];
    const float* ba  = (const float*)d_in[8];
    const float* Wtb = (const float*)d_in[9];
    const float* btb = (const float*)d_in[10];
    const float* Wp1 = (const float*)d_in[11];
    const float* bp1 = (const float*)d_in[12];
    const float* Wp2 = (const float*)d_in[13];
    const float* bp2 = (const float*)d_in[14];

    const size_t seq_bytes = (size_t)256 * T_ * LAT * sizeof(_Float16);   // 67MB
    const size_t xh_bytes  = (size_t)256 * T_ * IND * sizeof(_Float16);   // 16.8MB

    if (ws_size >= seq_bytes + xh_bytes) {
        _Float16* seq = (_Float16*)d_ws;
        _Float16* xh  = (_Float16*)((char*)d_ws + seq_bytes);
        x2h<<<dim3(2048), dim3(256), 0, stream>>>(x, xh);
        cfc_scan2<true><<<dim3(16), dim3(512), 0, stream>>>(
            x, xh, Wb, bb, W1, b1, W2, b2, Wa, ba, Wtb, btb, seq);
        cfc_proj<<<dim3(2048), dim3(256), 0, stream>>>(
            seq, Wp1, bp1, Wp2, bp2, (float*)d_out);
    } else if (ws_size >= seq_bytes) {
        _Float16* seq = (_Float16*)d_ws;
        cfc_scan2<false><<<dim3(16), dim3(512), 0, stream>>>(
            x, nullptr, Wb, bb, W1, b1, W2, b2, Wa, ba, Wtb, btb, seq);
        cfc_proj<<<dim3(2048), dim3(256), 0, stream>>>(
            seq, Wp1, bp1, Wp2, bp2, (float*)d_out);
    } else {
        cfc_fused_fb<<<dim3(16), dim3(512), 0, stream>>>(
            x, Wb, bb, W1, b1, W2, b2, Wa, ba, Wtb, btb, Wp1, bp1, Wp2, bp2,
            (float*)d_out);
    }
}

// Round 7
// 759.062 us; speedup vs baseline: 1.4332x; 1.4332x over previous
//
#include <hip/hip_runtime.h>

// CfC, round 7: R5 structure, un-bundled improvements.
//  - seq stores back in phase B from hv registers (R5 form; no ha->store dep)
//  - barrier_lds (lgkmcnt-only; no vmcnt store drain per step)
//  - XH: x pre-converted to fp16 by x2h kernel (ws-gated)
//  - phase B: af0/2/4 chains, af1/3/5 chains, then blend sub0, blend sub1
//    (no LDS writes between MFMA groups; blend0 trans overlaps group-1 MFMAs)
//  K1 cfc_scan3<XH> 16x512; K2 cfc_proj unchanged; fallback fused R3.

#define T_   512
#define IND  64
#define LAT  256
#define BBD  128
#define OUTD 64
#define HLF  128

typedef _Float16 half8 __attribute__((ext_vector_type(8)));
typedef float    f32x4 __attribute__((ext_vector_type(4)));
typedef float    f4    __attribute__((ext_vector_type(4)));

#define MFMA16(a,b,c) __builtin_amdgcn_mfma_f32_16x16x32_f16((a),(b),(c),0,0,0)

__device__ __forceinline__ float ex2(float x)   { return __builtin_amdgcn_exp2f(x); }
__device__ __forceinline__ float rcpf_(float x) { return __builtin_amdgcn_rcpf(x); }
// LDS-only barrier: ds ops visible, global stores NOT drained.
__device__ __forceinline__ void barrier_lds() {
    asm volatile("s_waitcnt lgkmcnt(0)\n\ts_barrier" ::: "memory");
}

// ====================== K0: x -> fp16 pre-convert ===========================
__global__ void __launch_bounds__(256) x2h(const float* __restrict__ x,
                                           _Float16* __restrict__ xh) {
    const size_t i = ((size_t)blockIdx.x * 256 + threadIdx.x) * 16;
    f4 a = *(const f4*)(x + i);
    f4 b = *(const f4*)(x + i + 4);
    f4 c = *(const f4*)(x + i + 8);
    f4 d = *(const f4*)(x + i + 12);
    half8 lo, hi;
    #pragma unroll
    for (int e = 0; e < 4; ++e) {
        lo[e] = (_Float16)a[e]; lo[e+4] = (_Float16)b[e];
        hi[e] = (_Float16)c[e]; hi[e+4] = (_Float16)d[e];
    }
    *(half8*)(xh + i)     = lo;
    *(half8*)(xh + i + 8) = hi;
}

// ============================ K1: recurrence scan ============================
template<bool XH>
__global__ void __launch_bounds__(512, 2) cfc_scan3(
    const float* __restrict__ x, const _Float16* __restrict__ xh,
    const float* __restrict__ Wb,  const float* __restrict__ bb,
    const float* __restrict__ W1,  const float* __restrict__ b1,
    const float* __restrict__ W2,  const float* __restrict__ b2,
    const float* __restrict__ Wa,  const float* __restrict__ ba,
    const float* __restrict__ Wtb, const float* __restrict__ btb,
    _Float16* __restrict__ seq)
{
    const int tid  = threadIdx.x;
    const int wv   = tid >> 6;
    const int lane = tid & 63;
    const int l15  = lane & 15;
    const int lg   = lane >> 4;
    const int krow = lg << 3;
    const int b0   = blockIdx.x << 4;

    __shared__ __align__(16) _Float16 hbuf[16*LAT];   // 8KB
    __shared__ __align__(16) _Float16 zbuf[16*BBD];   // 4KB

    half8 WbB[10];
    {
        const int col = (wv<<4) + l15;
        #pragma unroll
        for (int kk = 0; kk < 10; ++kk) {
            half8 v;
            #pragma unroll
            for (int e = 0; e < 8; ++e)
                v[e] = (_Float16)Wb[(kk*32 + krow + e)*BBD + col];
            WbB[kk] = v;
        }
    }
    half8 WfB[6][4];   // 0,1=W1 2,3=W2 4,5=Wa+Wtb ; 1.7159 folded
    #pragma unroll
    for (int t6 = 0; t6 < 6; ++t6) {
        const int m   = t6 >> 1;
        const int col = (wv<<5) + ((t6&1)<<4) + l15;
        const float* Wm = (m==0) ? W1 : ((m==1) ? W2 : Wa);
        #pragma unroll
        for (int kk = 0; kk < 4; ++kk) {
            half8 v;
            #pragma unroll
            for (int e = 0; e < 8; ++e) {
                const int k = kk*32 + krow + e;
                float f = Wm[k*LAT + col];
                if (m == 2) f += Wtb[k*LAT + col];
                v[e] = (_Float16)(1.7159f * f);
            }
            WfB[t6][kk] = v;
        }
    }

    const float K1 = 1.4426950408889634f;
    const float K2 = 2.8853900817779268f;
    const float KZ = 1.9216698144680396f;
    const int cz  = (wv<<4) + l15;
    const int cf0 = (wv<<5) + l15;
    const int cf1 = cf0 + 16;
    const float bbr   = bb[cz] * KZ;
    const float b1r0  = b1[cf0]*K2,  b1r1  = b1[cf1]*K2;
    const float b2r0  = b2[cf0]*K2,  b2r1  = b2[cf1]*K2;
    const float batr0 = (ba[cf0]+btb[cf0])*K1, batr1 = (ba[cf1]+btb[cf1])*K1;

    // x pointers / prefetch
    const float*    xrow  = x  + (size_t)(b0 + l15) * (T_*IND);
    const _Float16* xhrow = xh + (size_t)(b0 + l15) * (T_*IND);
    f4 xq[4];
    half8 xn0, xn1;
    if (XH) {
        xn0 = *(const half8*)(xhrow + krow);
        xn1 = *(const half8*)(xhrow + 32 + krow);
    } else {
        #pragma unroll
        for (int q = 0; q < 4; ++q)
            xq[q] = *(const f4*)(xrow + ((q>>1)*32 + krow + (q&1)*4));
    }

    half8 ha[8];
    {
        half8 hz;
        #pragma unroll
        for (int e = 0; e < 8; ++e) hz[e] = (_Float16)0.f;
        #pragma unroll
        for (int i = 0; i < 8; ++i) ha[i] = hz;
    }
    const f32x4 fz = {0.f, 0.f, 0.f, 0.f};
    // seq store base (R5 form): per-thread scalar stores from hv
    _Float16* const sbase = seq + (size_t)(b0 + (lg<<2)) * (T_*LAT) + (wv<<5) + l15;

    #pragma unroll 1
    for (int t = 0; t < T_; ++t) {
        // ============================ PHASE A ============================
        if (t > 0) {
            #pragma unroll
            for (int kk = 0; kk < 8; ++kk)
                ha[kk] = *(const half8*)&hbuf[(l15*LAT + kk*32 + krow) ^ ((l15&7)<<3)];
        }

        // current x fragments + prefetch next
        half8 xa0, xa1;
        if (XH) {
            xa0 = xn0; xa1 = xn1;
            const int tn = (t < T_-1) ? (t+1) : t;
            xn0 = *(const half8*)(xhrow + tn*IND + krow);
            xn1 = *(const half8*)(xhrow + tn*IND + 32 + krow);
        } else {
            #pragma unroll
            for (int e = 0; e < 4; ++e) {
                xa0[e]   = (_Float16)xq[0][e];
                xa0[e+4] = (_Float16)xq[1][e];
                xa1[e]   = (_Float16)xq[2][e];
                xa1[e+4] = (_Float16)xq[3][e];
            }
            const int tn = (t < T_-1) ? (t+1) : t;
            const float* p = xrow + tn*IND + krow;
            #pragma unroll
            for (int q = 0; q < 4; ++q)
                xq[q] = *(const f4*)(p + (q>>1)*32 + (q&1)*4);
        }

        // GEMM_h: 3 parallel chains (x-chain first: doesn't need ha)
        f32x4 azx = MFMA16(xa0, WbB[0], fz);
        azx = MFMA16(xa1, WbB[1], azx);
        f32x4 az0 = MFMA16(ha[0], WbB[2], fz);
        f32x4 az1 = MFMA16(ha[1], WbB[3], fz);
        #pragma unroll
        for (int kk = 2; kk < 8; kk += 2) {
            az0 = MFMA16(ha[kk],   WbB[kk+2], az0);
            az1 = MFMA16(ha[kk+1], WbB[kk+3], az1);
        }
        const f32x4 az = (azx + az0) + az1;

        #pragma unroll
        for (int r = 0; r < 4; ++r) {
            const float E = ex2(__builtin_fmaf(az[r], KZ, bbr));
            const float z = __builtin_fmaf(-2.f, rcpf_(E + 1.f), 1.f);
            const int row = (lg<<2) + r;
            zbuf[(row*BBD + cz) ^ ((row&7)<<3)] = (_Float16)z;
        }
        barrier_lds();   // bar 1: zbuf ready

        // ============================ PHASE B ============================
        half8 za[4];
        #pragma unroll
        for (int kk = 0; kk < 4; ++kk)
            za[kk] = *(const half8*)&zbuf[(l15*BBD + kk*32 + krow) ^ ((l15&7)<<3)];

        // group 0: tiles 0,2,4
        f32x4 af0 = fz, af2 = fz, af4 = fz;
        #pragma unroll
        for (int kk = 0; kk < 4; ++kk) {
            af0 = MFMA16(za[kk], WfB[0][kk], af0);
            af2 = MFMA16(za[kk], WfB[2][kk], af2);
            af4 = MFMA16(za[kk], WfB[4][kk], af4);
        }
        // group 1: tiles 1,3,5 (independent; blend0 trans can fill its shadow)
        f32x4 af1 = fz, af3 = fz, af5 = fz;
        #pragma unroll
        for (int kk = 0; kk < 4; ++kk) {
            af1 = MFMA16(za[kk], WfB[1][kk], af1);
            af3 = MFMA16(za[kk], WfB[3][kk], af3);
            af5 = MFMA16(za[kk], WfB[5][kk], af5);
        }

        _Float16* const sp = sbase + (size_t)t * LAT;
        // blend sub0 (consumes group 0)
        #pragma unroll
        for (int r = 0; r < 4; ++r) {
            const float E1 = ex2(__builtin_fmaf(af0[r], K2, b1r0));
            const float E2 = ex2(__builtin_fmaf(af2[r], K2, b2r0));
            const float E3 = ex2(__builtin_fmaf(af4[r], K1, batr0));
            const float p1_ = E1 + 1.f;
            const float p2_ = E2 + 1.f;
            const float p3_ = E3 + 1.f;
            const float num = __builtin_fmaf(E3, p1_, p2_);
            const float hv  = __builtin_fmaf(-2.f*num, rcpf_(p1_*p2_*p3_), 1.f);
            const _Float16 hh = (_Float16)hv;
            const int row = (lg<<2) + r;
            hbuf[(row*LAT + (wv<<5) + l15) ^ ((row&7)<<3)] = hh;
            sp[(size_t)r*(T_*LAT)] = hh;
        }
        // blend sub1 (consumes group 1)
        #pragma unroll
        for (int r = 0; r < 4; ++r) {
            const float E1 = ex2(__builtin_fmaf(af1[r], K2, b1r1));
            const float E2 = ex2(__builtin_fmaf(af3[r], K2, b2r1));
            const float E3 = ex2(__builtin_fmaf(af5[r], K1, batr1));
            const float p1_ = E1 + 1.f;
            const float p2_ = E2 + 1.f;
            const float p3_ = E3 + 1.f;
            const float num = __builtin_fmaf(E3, p1_, p2_);
            const float hv  = __builtin_fmaf(-2.f*num, rcpf_(p1_*p2_*p3_), 1.f);
            const _Float16 hh = (_Float16)hv;
            const int row = (lg<<2) + r;
            hbuf[(row*LAT + (wv<<5) + 16 + l15) ^ ((row&7)<<3)] = hh;
            sp[(size_t)r*(T_*LAT) + 16] = hh;
        }
        barrier_lds();   // bar 2: hbuf ready for t+1
    }
}

// ============================ K2: projection =================================
__global__ void __launch_bounds__(256, 2) cfc_proj(
    const _Float16* __restrict__ seq,
    const float* __restrict__ Wp1, const float* __restrict__ bp1,
    const float* __restrict__ Wp2, const float* __restrict__ bp2,
    float* __restrict__ out)
{
    const int tid  = threadIdx.x;
    const int wv   = tid >> 6;      // 0..3
    const int lane = tid & 63;
    const int l15  = lane & 15;
    const int lg   = lane >> 4;
    const int krow = lg << 3;

    __shared__ __align__(16) _Float16 wp1l[64*512];      // 64KB
    __shared__ __align__(16) _Float16 wp2l[16*512];      // 16KB
    __shared__ __align__(16) _Float16 dbuf[4][16*HLF];   // 16KB

    #pragma unroll
    for (int f = 0; f < 16; ++f) {
        const int g = wv*16 + f, tt = g >> 3, kk = g & 7;
        half8 v;
        #pragma unroll
        for (int e = 0; e < 8; ++e)
            v[e] = (_Float16)Wp1[(kk*32 + krow + e)*HLF + (tt<<4) + l15];
        *(half8*)&wp1l[g*512 + (lane<<3)] = v;
    }
    #pragma unroll
    for (int f = 0; f < 4; ++f) {
        const int g = wv*4 + f, tt = g >> 2, kk = g & 3;
        half8 v;
        #pragma unroll
        for (int e = 0; e < 8; ++e)
            v[e] = (_Float16)Wp2[(kk*32 + krow + e)*OUTD + (tt<<4) + l15];
        *(half8*)&wp2l[g*512 + (lane<<3)] = v;
    }

    const float K1 = 1.4426950408889634f;
    float bp1v[8], bp1kv[8];
    #pragma unroll
    for (int tt = 0; tt < 8; ++tt) {
        bp1v[tt]  = bp1[(tt<<4) + l15];
        bp1kv[tt] = bp1v[tt] * K1;
    }
    float bp2v[4];
    #pragma unroll
    for (int tt = 0; tt < 4; ++tt) bp2v[tt] = bp2[(tt<<4) + l15];

    __syncthreads();

    const int m0 = (blockIdx.x*4 + wv) << 4;
    const f32x4 fz = {0.f, 0.f, 0.f, 0.f};

    half8 ha[8];
    {
        const _Float16* ap = seq + (size_t)(m0 + l15)*LAT + krow;
        #pragma unroll
        for (int kk = 0; kk < 8; ++kk)
            ha[kk] = *(const half8*)(ap + kk*32);
    }

    #pragma unroll
    for (int tt = 0; tt < 8; ++tt) {
        f32x4 a0 = fz, a1 = fz;
        #pragma unroll
        for (int kk = 0; kk < 8; kk += 2) {
            a0 = MFMA16(ha[kk],   *(const half8*)&wp1l[((tt<<3)+kk  )*512 + (lane<<3)], a0);
            a1 = MFMA16(ha[kk+1], *(const half8*)&wp1l[((tt<<3)+kk+1)*512 + (lane<<3)], a1);
        }
        const f32x4 ap = a0 + a1;
        #pragma unroll
        for (int r = 0; r < 4; ++r) {
            const float v  = ap[r] + bp1v[tt];
            const float E  = ex2(__builtin_fmaf(ap[r], K1, bp1kv[tt]));
            const float sg = rcpf_(E + 1.f);
            const float hd = __builtin_fmaf(-v, sg, v);
            const int row = (lg<<2) + r;
            dbuf[wv][(row*HLF + (tt<<4) + l15) ^ ((row&7)<<3)] = (_Float16)hd;
        }
    }

    half8 pa[4];
    #pragma unroll
    for (int kk = 0; kk < 4; ++kk)
        pa[kk] = *(const half8*)&dbuf[wv][(l15*HLF + kk*32 + krow) ^ ((l15&7)<<3)];
    #pragma unroll
    for (int tt = 0; tt < 4; ++tt) {
        f32x4 ao = fz;
        #pragma unroll
        for (int kk = 0; kk < 4; ++kk)
            ao = MFMA16(pa[kk], *(const half8*)&wp2l[((tt<<2)+kk)*512 + (lane<<3)], ao);
        #pragma unroll
        for (int r = 0; r < 4; ++r)
            out[(size_t)(m0 + (lg<<2) + r)*OUTD + (tt<<4) + l15] = ao[r] + bp2v[tt];
    }
}

// ==================== fallback: R3 fused kernel (ws too small) ===============
__global__ void __launch_bounds__(512, 2) cfc_fused_fb(
    const float* __restrict__ x,
    const float* __restrict__ Wb,  const float* __restrict__ bb,
    const float* __restrict__ W1,  const float* __restrict__ b1,
    const float* __restrict__ W2,  const float* __restrict__ b2,
    const float* __restrict__ Wa,  const float* __restrict__ ba,
    const float* __restrict__ Wtb, const float* __restrict__ btb,
    const float* __restrict__ Wp1, const float* __restrict__ bp1,
    const float* __restrict__ Wp2, const float* __restrict__ bp2,
    float* __restrict__ out)
{
    const int tid  = threadIdx.x;
    const int wv   = tid >> 6;
    const int lane = tid & 63;
    const int l15  = lane & 15;
    const int lg   = lane >> 4;
    const int krow = lg << 3;
    const int b0   = blockIdx.x << 4;

    __shared__ __align__(16) _Float16 hbuf[16*LAT];
    __shared__ __align__(16) _Float16 zbuf[16*BBD];
    __shared__ __align__(16) _Float16 dbuf[16*HLF];
    __shared__ __align__(16) _Float16 wp1l[64*512];
    __shared__ __align__(16) _Float16 wp2l[16*512];

    half8 WbB[10];
    {
        const int col = (wv<<4) + l15;
        #pragma unroll
        for (int kk = 0; kk < 10; ++kk) {
            half8 v;
            #pragma unroll
            for (int e = 0; e < 8; ++e)
                v[e] = (_Float16)Wb[(kk*32 + krow + e)*BBD + col];
            WbB[kk] = v;
        }
    }
    half8 WfB[6][4];
    #pragma unroll
    for (int t6 = 0; t6 < 6; ++t6) {
        const int m   = t6 >> 1;
        const int col = (wv<<5) + ((t6&1)<<4) + l15;
        const float* Wm = (m==0) ? W1 : ((m==1) ? W2 : Wa);
        #pragma unroll
        for (int kk = 0; kk < 4; ++kk) {
            half8 v;
            #pragma unroll
            for (int e = 0; e < 8; ++e) {
                const int k = kk*32 + krow + e;
                float f = Wm[k*LAT + col];
                if (m == 2) f += Wtb[k*LAT + col];
                v[e] = (_Float16)(1.7159f * f);
            }
            WfB[t6][kk] = v;
        }
    }
    {
        const int col = (wv<<4) + l15;
        #pragma unroll
        for (int kk = 0; kk < 8; ++kk) {
            half8 v;
            #pragma unroll
            for (int e = 0; e < 8; ++e)
                v[e] = (_Float16)Wp1[(kk*32 + krow + e)*HLF + col];
            *(half8*)&wp1l[((wv<<3) + kk)*512 + (lane<<3)] = v;
        }
        if (wv < 4) {
            #pragma unroll
            for (int kk = 0; kk < 4; ++kk) {
                half8 v;
                #pragma unroll
                for (int e = 0; e < 8; ++e)
                    v[e] = (_Float16)Wp2[(kk*32 + krow + e)*OUTD + col];
                *(half8*)&wp2l[((wv<<2) + kk)*512 + (lane<<3)] = v;
            }
        }
    }
    const _Float16* const wp1p = &wp1l[(wv<<3)*512 + (lane<<3)];
    const _Float16* const wp2p = &wp2l[(wv<<2)*512 + (lane<<3)];

    const float K1 = 1.4426950408889634f;
    const float K2 = 2.8853900817779268f;
    const float KZ = 1.9216698144680396f;
    const int cz  = (wv<<4) + l15;
    const int cf0 = (wv<<5) + l15;
    const int cf1 = cf0 + 16;
    const float bbr   = bb[cz] * KZ;
    const float b1r0  = b1[cf0]*K2,  b1r1  = b1[cf1]*K2;
    const float b2r0  = b2[cf0]*K2,  b2r1  = b2[cf1]*K2;
    const float batr0 = (ba[cf0]+btb[cf0])*K1, batr1 = (ba[cf1]+btb[cf1])*K1;
    const float bp1a  = bp1[cz];
    const float bp1k  = bp1a * K1;
    const float bp2r  = (wv < 4) ? bp2[cz] : 0.f;

    __syncthreads();

    const float* xrow = x + (size_t)(b0 + l15) * (T_*IND);
    f4 xq[4];
    #pragma unroll
    for (int q = 0; q < 4; ++q)
        xq[q] = *(const f4*)(xrow + ((q>>1)*32 + krow + (q&1)*4));

    half8 ha[8];
    {
        half8 hz;
        #pragma unroll
        for (int e = 0; e < 8; ++e) hz[e] = (_Float16)0.f;
        #pragma unroll
        for (int i = 0; i < 8; ++i) ha[i] = hz;
    }
    const f32x4 fz = {0.f, 0.f, 0.f, 0.f};
    float* const obase = out + (size_t)(b0 + (lg<<2)) * (T_*OUTD) + (wv<<4) + l15;

    #pragma unroll 1
    for (int t = 0; t < T_; ++t) {
        if (t > 0) {
            #pragma unroll
            for (int kk = 0; kk < 8; ++kk)
                ha[kk] = *(const half8*)&hbuf[(l15*LAT + kk*32 + krow) ^ ((l15&7)<<3)];
        }
        half8 xa0, xa1;
        #pragma unroll
        for (int e = 0; e < 4; ++e) {
            xa0[e]   = (_Float16)xq[0][e];
            xa0[e+4] = (_Float16)xq[1][e];
            xa1[e]   = (_Float16)xq[2][e];
            xa1[e+4] = (_Float16)xq[3][e];
        }
        {
            const int tn = (t < T_-1) ? (t+1) : t;
            const float* p = xrow + tn*IND + krow;
            #pragma unroll
            for (int q = 0; q < 4; ++q)
                xq[q] = *(const f4*)(p + (q>>1)*32 + (q&1)*4);
        }
        f32x4 az0 = MFMA16(xa0, WbB[0], fz);
        f32x4 az1 = MFMA16(xa1, WbB[1], fz);
        #pragma unroll
        for (int kk = 0; kk < 8; kk += 2) {
            az0 = MFMA16(ha[kk],   WbB[kk+2], az0);
            az1 = MFMA16(ha[kk+1], WbB[kk+3], az1);
        }
        const f32x4 az = az0 + az1;
        #pragma unroll
        for (int r = 0; r < 4; ++r) {
            const float E = ex2(__builtin_fmaf(az[r], KZ, bbr));
            const float z = __builtin_fmaf(-2.f, rcpf_(E + 1.f), 1.f);
            const int row = (lg<<2) + r;
            zbuf[(row*BBD + cz) ^ ((row&7)<<3)] = (_Float16)z;
        }
        if (t > 0) {
            f32x4 ap0 = fz, ap1 = fz;
            #pragma unroll
            for (int kk = 0; kk < 8; kk += 2) {
                ap0 = MFMA16(ha[kk],   *(const half8*)(wp1p +  kk   *512), ap0);
                ap1 = MFMA16(ha[kk+1], *(const half8*)(wp1p + (kk+1)*512), ap1);
            }
            const f32x4 ap = ap0 + ap1;
            #pragma unroll
            for (int r = 0; r < 4; ++r) {
                const float v  = ap[r] + bp1a;
                const float E  = ex2(__builtin_fmaf(ap[r], K1, bp1k));
                const float sg = rcpf_(E + 1.f);
                const float hd = __builtin_fmaf(-v, sg, v);
                const int row = (lg<<2) + r;
                dbuf[(row*HLF + cz) ^ ((row&7)<<3)] = (_Float16)hd;
            }
        }
        __syncthreads();

        half8 za[4];
        #pragma unroll
        for (int kk = 0; kk < 4; ++kk)
            za[kk] = *(const half8*)&zbuf[(l15*BBD + kk*32 + krow) ^ ((l15&7)<<3)];
        f32x4 af[6];
        #pragma unroll
        for (int i = 0; i < 6; ++i) af[i] = fz;
        #pragma unroll
        for (int kk = 0; kk < 4; ++kk) {
            #pragma unroll
            for (int i = 0; i < 6; ++i) af[i] = MFMA16(za[kk], WfB[i][kk], af[i]);
        }
        #pragma unroll
        for (int sub = 0; sub < 2; ++sub) {
            const float b1r  = sub ? b1r1  : b1r0;
            const float b2r  = sub ? b2r1  : b2r0;
            const float batr = sub ? batr1 : batr0;
            #pragma unroll
            for (int r = 0; r < 4; ++r) {
                const float E1 = ex2(__builtin_fmaf(af[0+sub][r], K2, b1r));
                const float E2 = ex2(__builtin_fmaf(af[2+sub][r], K2, b2r));
                const float E3 = ex2(__builtin_fmaf(af[4+sub][r], K1, batr));
                const float p1_ = E1 + 1.f;
                const float p2_ = E2 + 1.f;
                const float p3_ = E3 + 1.f;
                const float num = __builtin_fmaf(E3, p1_, p2_);
                const float hv  = __builtin_fmaf(-2.f*num, rcpf_(p1_*p2_*p3_), 1.f);
                const int row = (lg<<2) + r;
                hbuf[(row*LAT + (wv<<5) + (sub<<4) + l15) ^ ((row&7)<<3)] = (_Float16)hv;
            }
        }
        if (t > 0 && wv < 4) {
            f32x4 ao = fz;
            #pragma unroll
            for (int kk = 0; kk < 4; ++kk) {
                const half8 aa = *(const half8*)&dbuf[(l15*HLF + kk*32 + krow) ^ ((l15&7)<<3)];
                ao = MFMA16(aa, *(const half8*)(wp2p + kk*512), ao);
            }
            #pragma unroll
            for (int r = 0; r < 4; ++r)
                obase[(size_t)r*(T_*OUTD) + (size_t)(t-1)*OUTD] = ao[r] + bp2r;
        }
        __syncthreads();
    }
    {
        #pragma unroll
        for (int kk = 0; kk < 8; ++kk)
            ha[kk] = *(const half8*)&hbuf[(l15*LAT + kk*32 + krow) ^ ((l15&7)<<3)];
        f32x4 ap0 = fz, ap1 = fz;
        #pragma unroll
        for (int kk = 0; kk < 8; kk += 2) {
            ap0 = MFMA16(ha[kk],   *(const half8*)(wp1p +  kk   *512), ap0);
            ap1 = MFMA16(ha[kk+1], *(const half8*)(wp1p + (kk+1)*512), ap1);
        }
        const f32x4 ap = ap0 + ap1;
        #pragma unroll
        for (int r = 0; r < 4; ++r) {
            const float v  = ap[r] + bp1a;
            const float E  = ex2(__builtin_fmaf(ap[r], K1, bp1k));
            const float sg = rcpf_(E + 1.f);
            const float hd = __builtin_fmaf(-v, sg, v);
            const int row = (lg<<2) + r;
            dbuf[(row*HLF + cz) ^ ((row&7)<<3)] = (_Float16)hd;
        }
        __syncthreads();
        if (wv < 4) {
            f32x4 ao = fz;
            #pragma unroll
            for (int kk = 0; kk < 4; ++kk) {
                const half8 aa = *(const half8*)&dbuf[(l15*HLF + kk*32 + krow) ^ ((l15&7)<<3)];
                ao = MFMA16(aa, *(const half8*)(wp2p + kk*512), ao);
            }
            #pragma unroll
            for (int r = 0; r < 4; ++r)
                obase[(size_t)r*(T_*OUTD) + (size_t)(T_-1)*OUTD] = ao[r] + bp2r;
        }
    }
}

extern "C" void kernel_launch(void* const* d_in, const int* in_sizes, int n_in,
                              void* d_out, int out_size, void* d_ws, size_t ws_size,
                              hipStream_t stream) {
    (void)in_sizes; (void)n_in; (void)out_size;
    const float* x   = (const float*)d_in[0];
    const float* Wb  = (const float*)d_in[1];
    const float* bb  = (const float*)d_in[2];
    const float* W1  = (const float*)d_in[3];
    const float* b1  = (const float*)d_in[4];
    const float* W2  = (const float*)d_in[5];
    const float* b2  = (const float*)d_in[6];
    const float* Wa  = (const float*)d_in[7];
    const float* ba  = (const float*)d_in[8];
    const float* Wtb = (const float*)d_in[9];
    const float* btb = (const float*)d_in[10];
    const float* Wp1 = (const float*)d_in[11];
    const float* bp1 = (const float*)d_in[12];
    const float* Wp2 = (const float*)d_in[13];
    const float* bp2 = (const float*)d_in[14];

    const size_t seq_bytes = (size_t)256 * T_ * LAT * sizeof(_Float16);   // 67MB
    const size_t xh_bytes  = (size_t)256 * T_ * IND * sizeof(_Float16);   // 16.8MB

    if (ws_size >= seq_bytes + xh_bytes) {
        _Float16* seq = (_Float16*)d_ws;
        _Float16* xh  = (_Float16*)((char*)d_ws + seq_bytes);
        x2h<<<dim3(2048), dim3(256), 0, stream>>>(x, xh);
        cfc_scan3<true><<<dim3(16), dim3(512), 0, stream>>>(
            x, xh, Wb, bb, W1, b1, W2, b2, Wa, ba, Wtb, btb, seq);
        cfc_proj<<<dim3(2048), dim3(256), 0, stream>>>(
            seq, Wp1, bp1, Wp2, bp2, (float*)d_out);
    } else if (ws_size >= seq_bytes) {
        _Float16* seq = (_Float16*)d_ws;
        cfc_scan3<false><<<dim3(16), dim3(512), 0, stream>>>(
            x, nullptr, Wb, bb, W1, b1, W2, b2, Wa, ba, Wtb, btb, seq);
        cfc_proj<<<dim3(2048), dim3(256), 0, stream>>>(
            seq, Wp1, bp1, Wp2, bp2, (float*)d_out);
    } else {
        cfc_fused_fb<<<dim3(16), dim3(512), 0, stream>>>(
            x, Wb, bb, W1, b1, W2, b2, Wa, ba, Wtb, btb, Wp1, bp1, Wp2, bp2,
            (float*)d_out);
    }
}

// Round 8
// 751.306 us; speedup vs baseline: 1.4480x; 1.0103x over previous
//
#include <hip/hip_runtime.h>

// CfC, round 8: R7 + sched_group_barrier-pinned MFMA/trans interleave in phase B.
//  - branchless scan body (hbuf pre-zeroed; ha reload unconditional)
//  - phase B fenced with sched_barrier(0); SGB pattern: DSR4, M12, 4x[M3,V19,DSW1,VMW1]
//  - everything else identical to R7 (XH pre-convert, lgkm-only barriers,
//    seq stores from hv in phase B, g0/g1 chain split)

#define T_   512
#define IND  64
#define LAT  256
#define BBD  128
#define OUTD 64
#define HLF  128

typedef _Float16 half8 __attribute__((ext_vector_type(8)));
typedef float    f32x4 __attribute__((ext_vector_type(4)));
typedef float    f4    __attribute__((ext_vector_type(4)));

#define MFMA16(a,b,c) __builtin_amdgcn_mfma_f32_16x16x32_f16((a),(b),(c),0,0,0)

__device__ __forceinline__ float ex2(float x)   { return __builtin_amdgcn_exp2f(x); }
__device__ __forceinline__ float rcpf_(float x) { return __builtin_amdgcn_rcpf(x); }
__device__ __forceinline__ void barrier_lds() {
    asm volatile("s_waitcnt lgkmcnt(0)\n\ts_barrier" ::: "memory");
}

// ====================== K0: x -> fp16 pre-convert ===========================
__global__ void __launch_bounds__(256) x2h(const float* __restrict__ x,
                                           _Float16* __restrict__ xh) {
    const size_t i = ((size_t)blockIdx.x * 256 + threadIdx.x) * 16;
    f4 a = *(const f4*)(x + i);
    f4 b = *(const f4*)(x + i + 4);
    f4 c = *(const f4*)(x + i + 8);
    f4 d = *(const f4*)(x + i + 12);
    half8 lo, hi;
    #pragma unroll
    for (int e = 0; e < 4; ++e) {
        lo[e] = (_Float16)a[e]; lo[e+4] = (_Float16)b[e];
        hi[e] = (_Float16)c[e]; hi[e+4] = (_Float16)d[e];
    }
    *(half8*)(xh + i)     = lo;
    *(half8*)(xh + i + 8) = hi;
}

// ============================ K1: recurrence scan ============================
template<bool XH>
__global__ void __launch_bounds__(512, 2) cfc_scan4(
    const float* __restrict__ x, const _Float16* __restrict__ xh,
    const float* __restrict__ Wb,  const float* __restrict__ bb,
    const float* __restrict__ W1,  const float* __restrict__ b1,
    const float* __restrict__ W2,  const float* __restrict__ b2,
    const float* __restrict__ Wa,  const float* __restrict__ ba,
    const float* __restrict__ Wtb, const float* __restrict__ btb,
    _Float16* __restrict__ seq)
{
    const int tid  = threadIdx.x;
    const int wv   = tid >> 6;
    const int lane = tid & 63;
    const int l15  = lane & 15;
    const int lg   = lane >> 4;
    const int krow = lg << 3;
    const int b0   = blockIdx.x << 4;

    __shared__ __align__(16) _Float16 hbuf[16*LAT];   // 8KB
    __shared__ __align__(16) _Float16 zbuf[16*BBD];   // 4KB

    half8 WbB[10];
    {
        const int col = (wv<<4) + l15;
        #pragma unroll
        for (int kk = 0; kk < 10; ++kk) {
            half8 v;
            #pragma unroll
            for (int e = 0; e < 8; ++e)
                v[e] = (_Float16)Wb[(kk*32 + krow + e)*BBD + col];
            WbB[kk] = v;
        }
    }
    half8 WfB[6][4];   // 0,1=W1 2,3=W2 4,5=Wa+Wtb ; 1.7159 folded
    #pragma unroll
    for (int t6 = 0; t6 < 6; ++t6) {
        const int m   = t6 >> 1;
        const int col = (wv<<5) + ((t6&1)<<4) + l15;
        const float* Wm = (m==0) ? W1 : ((m==1) ? W2 : Wa);
        #pragma unroll
        for (int kk = 0; kk < 4; ++kk) {
            half8 v;
            #pragma unroll
            for (int e = 0; e < 8; ++e) {
                const int k = kk*32 + krow + e;
                float f = Wm[k*LAT + col];
                if (m == 2) f += Wtb[k*LAT + col];
                v[e] = (_Float16)(1.7159f * f);
            }
            WfB[t6][kk] = v;
        }
    }

    const float K1 = 1.4426950408889634f;
    const float K2 = 2.8853900817779268f;
    const float KZ = 1.9216698144680396f;
    const int cz  = (wv<<4) + l15;
    const int cf0 = (wv<<5) + l15;
    const int cf1 = cf0 + 16;
    const float bbr   = bb[cz] * KZ;
    const float b1r0  = b1[cf0]*K2,  b1r1  = b1[cf1]*K2;
    const float b2r0  = b2[cf0]*K2,  b2r1  = b2[cf1]*K2;
    const float batr0 = (ba[cf0]+btb[cf0])*K1, batr1 = (ba[cf1]+btb[cf1])*K1;

    // x pointers / prefetch
    const float*    xrow  = x  + (size_t)(b0 + l15) * (T_*IND);
    const _Float16* xhrow = xh + (size_t)(b0 + l15) * (T_*IND);
    f4 xq[4];
    half8 xn0, xn1;
    if (XH) {
        xn0 = *(const half8*)(xhrow + krow);
        xn1 = *(const half8*)(xhrow + 32 + krow);
    } else {
        #pragma unroll
        for (int q = 0; q < 4; ++q)
            xq[q] = *(const f4*)(xrow + ((q>>1)*32 + krow + (q&1)*4));
    }

    // pre-zero hbuf (h0 = 0) -> branchless loop body
    {
        half8 z8;
        #pragma unroll
        for (int e = 0; e < 8; ++e) z8[e] = (_Float16)0.f;
        ((half8*)hbuf)[tid] = z8;   // 512 thr x 16B = 8KB
    }
    barrier_lds();

    const f32x4 fz = {0.f, 0.f, 0.f, 0.f};
    _Float16* const sbase = seq + (size_t)(b0 + (lg<<2)) * (T_*LAT) + (wv<<5) + l15;

    #pragma unroll 1
    for (int t = 0; t < T_; ++t) {
        // ============================ PHASE A ============================
        half8 ha[8];
        #pragma unroll
        for (int kk = 0; kk < 8; ++kk)
            ha[kk] = *(const half8*)&hbuf[(l15*LAT + kk*32 + krow) ^ ((l15&7)<<3)];

        half8 xa0, xa1;
        if (XH) {
            xa0 = xn0; xa1 = xn1;
            const int tn = (t < T_-1) ? (t+1) : t;
            xn0 = *(const half8*)(xhrow + tn*IND + krow);
            xn1 = *(const half8*)(xhrow + tn*IND + 32 + krow);
        } else {
            #pragma unroll
            for (int e = 0; e < 4; ++e) {
                xa0[e]   = (_Float16)xq[0][e];
                xa0[e+4] = (_Float16)xq[1][e];
                xa1[e]   = (_Float16)xq[2][e];
                xa1[e+4] = (_Float16)xq[3][e];
            }
            const int tn = (t < T_-1) ? (t+1) : t;
            const float* p = xrow + tn*IND + krow;
            #pragma unroll
            for (int q = 0; q < 4; ++q)
                xq[q] = *(const f4*)(p + (q>>1)*32 + (q&1)*4);
        }

        // GEMM_h: 3 parallel chains
        f32x4 azx = MFMA16(xa0, WbB[0], fz);
        azx = MFMA16(xa1, WbB[1], azx);
        f32x4 az0 = MFMA16(ha[0], WbB[2], fz);
        f32x4 az1 = MFMA16(ha[1], WbB[3], fz);
        #pragma unroll
        for (int kk = 2; kk < 8; kk += 2) {
            az0 = MFMA16(ha[kk],   WbB[kk+2], az0);
            az1 = MFMA16(ha[kk+1], WbB[kk+3], az1);
        }
        const f32x4 az = (azx + az0) + az1;

        #pragma unroll
        for (int r = 0; r < 4; ++r) {
            const float E = ex2(__builtin_fmaf(az[r], KZ, bbr));
            const float z = __builtin_fmaf(-2.f, rcpf_(E + 1.f), 1.f);
            const int row = (lg<<2) + r;
            zbuf[(row*BBD + cz) ^ ((row&7)<<3)] = (_Float16)z;
        }
        barrier_lds();   // bar 1: zbuf ready
        __builtin_amdgcn_sched_barrier(0);   // fence: phase B is its own region

        // ============================ PHASE B ============================
        half8 za[4];
        #pragma unroll
        for (int kk = 0; kk < 4; ++kk)
            za[kk] = *(const half8*)&zbuf[(l15*BBD + kk*32 + krow) ^ ((l15&7)<<3)];

        // group 0: tiles 0,2,4 (12 MFMA)
        f32x4 af0 = fz, af2 = fz, af4 = fz;
        #pragma unroll
        for (int kk = 0; kk < 4; ++kk) {
            af0 = MFMA16(za[kk], WfB[0][kk], af0);
            af2 = MFMA16(za[kk], WfB[2][kk], af2);
            af4 = MFMA16(za[kk], WfB[4][kk], af4);
        }
        // group 1: tiles 1,3,5 (12 MFMA, independent of blend0)
        f32x4 af1 = fz, af3 = fz, af5 = fz;
        #pragma unroll
        for (int kk = 0; kk < 4; ++kk) {
            af1 = MFMA16(za[kk], WfB[1][kk], af1);
            af3 = MFMA16(za[kk], WfB[3][kk], af3);
            af5 = MFMA16(za[kk], WfB[5][kk], af5);
        }

        _Float16* const sp = sbase + (size_t)t * LAT;
        // blend sub0 (consumes group 0 only)
        #pragma unroll
        for (int r = 0; r < 4; ++r) {
            const float E1 = ex2(__builtin_fmaf(af0[r], K2, b1r0));
            const float E2 = ex2(__builtin_fmaf(af2[r], K2, b2r0));
            const float E3 = ex2(__builtin_fmaf(af4[r], K1, batr0));
            const float p1_ = E1 + 1.f;
            const float p2_ = E2 + 1.f;
            const float p3_ = E3 + 1.f;
            const float num = __builtin_fmaf(E3, p1_, p2_);
            const float hv  = __builtin_fmaf(-2.f*num, rcpf_(p1_*p2_*p3_), 1.f);
            const _Float16 hh = (_Float16)hv;
            const int row = (lg<<2) + r;
            hbuf[(row*LAT + (wv<<5) + l15) ^ ((row&7)<<3)] = hh;
            sp[(size_t)r*(T_*LAT)] = hh;
        }
        // blend sub1 (consumes group 1)
        #pragma unroll
        for (int r = 0; r < 4; ++r) {
            const float E1 = ex2(__builtin_fmaf(af1[r], K2, b1r1));
            const float E2 = ex2(__builtin_fmaf(af3[r], K2, b2r1));
            const float E3 = ex2(__builtin_fmaf(af5[r], K1, batr1));
            const float p1_ = E1 + 1.f;
            const float p2_ = E2 + 1.f;
            const float p3_ = E3 + 1.f;
            const float num = __builtin_fmaf(E3, p1_, p2_);
            const float hv  = __builtin_fmaf(-2.f*num, rcpf_(p1_*p2_*p3_), 1.f);
            const _Float16 hh = (_Float16)hv;
            const int row = (lg<<2) + r;
            hbuf[(row*LAT + (wv<<5) + 16 + l15) ^ ((row&7)<<3)] = hh;
            sp[(size_t)r*(T_*LAT) + 16] = hh;
        }

        // -------- pinned schedule: front-load MFMA, interleave blend0 --------
        __builtin_amdgcn_sched_group_barrier(0x100, 4, 0);   // 4 ds_read (za)
        __builtin_amdgcn_sched_group_barrier(0x008, 12, 0);  // af-g0
        __builtin_amdgcn_sched_group_barrier(0x008, 3, 0);   // af-g1 part
        __builtin_amdgcn_sched_group_barrier(0x002, 19, 0);  // blend0 VALU
        __builtin_amdgcn_sched_group_barrier(0x200, 1, 0);   // ds_write
        __builtin_amdgcn_sched_group_barrier(0x040, 1, 0);   // seq store
        __builtin_amdgcn_sched_group_barrier(0x008, 3, 0);
        __builtin_amdgcn_sched_group_barrier(0x002, 19, 0);
        __builtin_amdgcn_sched_group_barrier(0x200, 1, 0);
        __builtin_amdgcn_sched_group_barrier(0x040, 1, 0);
        __builtin_amdgcn_sched_group_barrier(0x008, 3, 0);
        __builtin_amdgcn_sched_group_barrier(0x002, 19, 0);
        __builtin_amdgcn_sched_group_barrier(0x200, 1, 0);
        __builtin_amdgcn_sched_group_barrier(0x040, 1, 0);
        __builtin_amdgcn_sched_group_barrier(0x008, 3, 0);
        __builtin_amdgcn_sched_group_barrier(0x002, 19, 0);
        __builtin_amdgcn_sched_group_barrier(0x200, 1, 0);
        __builtin_amdgcn_sched_group_barrier(0x040, 1, 0);
        // tail (blend1 + remaining stores) left unpinned
        __builtin_amdgcn_sched_barrier(0);   // fence before bar2
        barrier_lds();   // bar 2: hbuf ready for t+1
    }
}

// ============================ K2: projection =================================
__global__ void __launch_bounds__(256, 2) cfc_proj(
    const _Float16* __restrict__ seq,
    const float* __restrict__ Wp1, const float* __restrict__ bp1,
    const float* __restrict__ Wp2, const float* __restrict__ bp2,
    float* __restrict__ out)
{
    const int tid  = threadIdx.x;
    const int wv   = tid >> 6;      // 0..3
    const int lane = tid & 63;
    const int l15  = lane & 15;
    const int lg   = lane >> 4;
    const int krow = lg << 3;

    __shared__ __align__(16) _Float16 wp1l[64*512];      // 64KB
    __shared__ __align__(16) _Float16 wp2l[16*512];      // 16KB
    __shared__ __align__(16) _Float16 dbuf[4][16*HLF];   // 16KB

    #pragma unroll
    for (int f = 0; f < 16; ++f) {
        const int g = wv*16 + f, tt = g >> 3, kk = g & 7;
        half8 v;
        #pragma unroll
        for (int e = 0; e < 8; ++e)
            v[e] = (_Float16)Wp1[(kk*32 + krow + e)*HLF + (tt<<4) + l15];
        *(half8*)&wp1l[g*512 + (lane<<3)] = v;
    }
    #pragma unroll
    for (int f = 0; f < 4; ++f) {
        const int g = wv*4 + f, tt = g >> 2, kk = g & 3;
        half8 v;
        #pragma unroll
        for (int e = 0; e < 8; ++e)
            v[e] = (_Float16)Wp2[(kk*32 + krow + e)*OUTD + (tt<<4) + l15];
        *(half8*)&wp2l[g*512 + (lane<<3)] = v;
    }

    const float K1 = 1.4426950408889634f;
    float bp1v[8], bp1kv[8];
    #pragma unroll
    for (int tt = 0; tt < 8; ++tt) {
        bp1v[tt]  = bp1[(tt<<4) + l15];
        bp1kv[tt] = bp1v[tt] * K1;
    }
    float bp2v[4];
    #pragma unroll
    for (int tt = 0; tt < 4; ++tt) bp2v[tt] = bp2[(tt<<4) + l15];

    __syncthreads();

    const int m0 = (blockIdx.x*4 + wv) << 4;
    const f32x4 fz = {0.f, 0.f, 0.f, 0.f};

    half8 ha[8];
    {
        const _Float16* ap = seq + (size_t)(m0 + l15)*LAT + krow;
        #pragma unroll
        for (int kk = 0; kk < 8; ++kk)
            ha[kk] = *(const half8*)(ap + kk*32);
    }

    #pragma unroll
    for (int tt = 0; tt < 8; ++tt) {
        f32x4 a0 = fz, a1 = fz;
        #pragma unroll
        for (int kk = 0; kk < 8; kk += 2) {
            a0 = MFMA16(ha[kk],   *(const half8*)&wp1l[((tt<<3)+kk  )*512 + (lane<<3)], a0);
            a1 = MFMA16(ha[kk+1], *(const half8*)&wp1l[((tt<<3)+kk+1)*512 + (lane<<3)], a1);
        }
        const f32x4 ap = a0 + a1;
        #pragma unroll
        for (int r = 0; r < 4; ++r) {
            const float v  = ap[r] + bp1v[tt];
            const float E  = ex2(__builtin_fmaf(ap[r], K1, bp1kv[tt]));
            const float sg = rcpf_(E + 1.f);
            const float hd = __builtin_fmaf(-v, sg, v);
            const int row = (lg<<2) + r;
            dbuf[wv][(row*HLF + (tt<<4) + l15) ^ ((row&7)<<3)] = (_Float16)hd;
        }
    }

    half8 pa[4];
    #pragma unroll
    for (int kk = 0; kk < 4; ++kk)
        pa[kk] = *(const half8*)&dbuf[wv][(l15*HLF + kk*32 + krow) ^ ((l15&7)<<3)];
    #pragma unroll
    for (int tt = 0; tt < 4; ++tt) {
        f32x4 ao = fz;
        #pragma unroll
        for (int kk = 0; kk < 4; ++kk)
            ao = MFMA16(pa[kk], *(const half8*)&wp2l[((tt<<2)+kk)*512 + (lane<<3)], ao);
        #pragma unroll
        for (int r = 0; r < 4; ++r)
            out[(size_t)(m0 + (lg<<2) + r)*OUTD + (tt<<4) + l15] = ao[r] + bp2v[tt];
    }
}

// ==================== fallback: R3 fused kernel (ws too small) ===============
__global__ void __launch_bounds__(512, 2) cfc_fused_fb(
    const float* __restrict__ x,
    const float* __restrict__ Wb,  const float* __restrict__ bb,
    const float* __restrict__ W1,  const float* __restrict__ b1,
    const float* __restrict__ W2,  const float* __restrict__ b2,
    const float* __restrict__ Wa,  const float* __restrict__ ba,
    const float* __restrict__ Wtb, const float* __restrict__ btb,
    const float* __restrict__ Wp1, const float* __restrict__ bp1,
    const float* __restrict__ Wp2, const float* __restrict__ bp2,
    float* __restrict__ out)
{
    const int tid  = threadIdx.x;
    const int wv   = tid >> 6;
    const int lane = tid & 63;
    const int l15  = lane & 15;
    const int lg   = lane >> 4;
    const int krow = lg << 3;
    const int b0   = blockIdx.x << 4;

    __shared__ __align__(16) _Float16 hbuf[16*LAT];
    __shared__ __align__(16) _Float16 zbuf[16*BBD];
    __shared__ __align__(16) _Float16 dbuf[16*HLF];
    __shared__ __align__(16) _Float16 wp1l[64*512];
    __shared__ __align__(16) _Float16 wp2l[16*512];

    half8 WbB[10];
    {
        const int col = (wv<<4) + l15;
        #pragma unroll
        for (int kk = 0; kk < 10; ++kk) {
            half8 v;
            #pragma unroll
            for (int e = 0; e < 8; ++e)
                v[e] = (_Float16)Wb[(kk*32 + krow + e)*BBD + col];
            WbB[kk] = v;
        }
    }
    half8 WfB[6][4];
    #pragma unroll
    for (int t6 = 0; t6 < 6; ++t6) {
        const int m   = t6 >> 1;
        const int col = (wv<<5) + ((t6&1)<<4) + l15;
        const float* Wm = (m==0) ? W1 : ((m==1) ? W2 : Wa);
        #pragma unroll
        for (int kk = 0; kk < 4; ++kk) {
            half8 v;
            #pragma unroll
            for (int e = 0; e < 8; ++e) {
                const int k = kk*32 + krow + e;
                float f = Wm[k*LAT + col];
                if (m == 2) f += Wtb[k*LAT + col];
                v[e] = (_Float16)(1.7159f * f);
            }
            WfB[t6][kk] = v;
        }
    }
    {
        const int col = (wv<<4) + l15;
        #pragma unroll
        for (int kk = 0; kk < 8; ++kk) {
            half8 v;
            #pragma unroll
            for (int e = 0; e < 8; ++e)
                v[e] = (_Float16)Wp1[(kk*32 + krow + e)*HLF + col];
            *(half8*)&wp1l[((wv<<3) + kk)*512 + (lane<<3)] = v;
        }
        if (wv < 4) {
            #pragma unroll
            for (int kk = 0; kk < 4; ++kk) {
                half8 v;
                #pragma unroll
                for (int e = 0; e < 8; ++e)
                    v[e] = (_Float16)Wp2[(kk*32 + krow + e)*OUTD + col];
                *(half8*)&wp2l[((wv<<2) + kk)*512 + (lane<<3)] = v;
            }
        }
    }
    const _Float16* const wp1p = &wp1l[(wv<<3)*512 + (lane<<3)];
    const _Float16* const wp2p = &wp2l[(wv<<2)*512 + (lane<<3)];

    const float K1 = 1.4426950408889634f;
    const float K2 = 2.8853900817779268f;
    const float KZ = 1.9216698144680396f;
    const int cz  = (wv<<4) + l15;
    const int cf0 = (wv<<5) + l15;
    const int cf1 = cf0 + 16;
    const float bbr   = bb[cz] * KZ;
    const float b1r0  = b1[cf0]*K2,  b1r1  = b1[cf1]*K2;
    const float b2r0  = b2[cf0]*K2,  b2r1  = b2[cf1]*K2;
    const float batr0 = (ba[cf0]+btb[cf0])*K1, batr1 = (ba[cf1]+btb[cf1])*K1;
    const float bp1a  = bp1[cz];
    const float bp1k  = bp1a * K1;
    const float bp2r  = (wv < 4) ? bp2[cz] : 0.f;

    __syncthreads();

    const float* xrow = x + (size_t)(b0 + l15) * (T_*IND);
    f4 xq[4];
    #pragma unroll
    for (int q = 0; q < 4; ++q)
        xq[q] = *(const f4*)(xrow + ((q>>1)*32 + krow + (q&1)*4));

    half8 ha[8];
    {
        half8 hz;
        #pragma unroll
        for (int e = 0; e < 8; ++e) hz[e] = (_Float16)0.f;
        #pragma unroll
        for (int i = 0; i < 8; ++i) ha[i] = hz;
    }
    const f32x4 fz = {0.f, 0.f, 0.f, 0.f};
    float* const obase = out + (size_t)(b0 + (lg<<2)) * (T_*OUTD) + (wv<<4) + l15;

    #pragma unroll 1
    for (int t = 0; t < T_; ++t) {
        if (t > 0) {
            #pragma unroll
            for (int kk = 0; kk < 8; ++kk)
                ha[kk] = *(const half8*)&hbuf[(l15*LAT + kk*32 + krow) ^ ((l15&7)<<3)];
        }
        half8 xa0, xa1;
        #pragma unroll
        for (int e = 0; e < 4; ++e) {
            xa0[e]   = (_Float16)xq[0][e];
            xa0[e+4] = (_Float16)xq[1][e];
            xa1[e]   = (_Float16)xq[2][e];
            xa1[e+4] = (_Float16)xq[3][e];
        }
        {
            const int tn = (t < T_-1) ? (t+1) : t;
            const float* p = xrow + tn*IND + krow;
            #pragma unroll
            for (int q = 0; q < 4; ++q)
                xq[q] = *(const f4*)(p + (q>>1)*32 + (q&1)*4);
        }
        f32x4 az0 = MFMA16(xa0, WbB[0], fz);
        f32x4 az1 = MFMA16(xa1, WbB[1], fz);
        #pragma unroll
        for (int kk = 0; kk < 8; kk += 2) {
            az0 = MFMA16(ha[kk],   WbB[kk+2], az0);
            az1 = MFMA16(ha[kk+1], WbB[kk+3], az1);
        }
        const f32x4 az = az0 + az1;
        #pragma unroll
        for (int r = 0; r < 4; ++r) {
            const float E = ex2(__builtin_fmaf(az[r], KZ, bbr));
            const float z = __builtin_fmaf(-2.f, rcpf_(E + 1.f), 1.f);
            const int row = (lg<<2) + r;
            zbuf[(row*BBD + cz) ^ ((row&7)<<3)] = (_Float16)z;
        }
        if (t > 0) {
            f32x4 ap0 = fz, ap1 = fz;
            #pragma unroll
            for (int kk = 0; kk < 8; kk += 2) {
                ap0 = MFMA16(ha[kk],   *(const half8*)(wp1p +  kk   *512), ap0);
                ap1 = MFMA16(ha[kk+1], *(const half8*)(wp1p + (kk+1)*512), ap1);
            }
            const f32x4 ap = ap0 + ap1;
            #pragma unroll
            for (int r = 0; r < 4; ++r) {
                const float v  = ap[r] + bp1a;
                const float E  = ex2(__builtin_fmaf(ap[r], K1, bp1k));
                const float sg = rcpf_(E + 1.f);
                const float hd = __builtin_fmaf(-v, sg, v);
                const int row = (lg<<2) + r;
                dbuf[(row*HLF + cz) ^ ((row&7)<<3)] = (_Float16)hd;
            }
        }
        __syncthreads();

        half8 za[4];
        #pragma unroll
        for (int kk = 0; kk < 4; ++kk)
            za[kk] = *(const half8*)&zbuf[(l15*BBD + kk*32 + krow) ^ ((l15&7)<<3)];
        f32x4 af[6];
        #pragma unroll
        for (int i = 0; i < 6; ++i) af[i] = fz;
        #pragma unroll
        for (int kk = 0; kk < 4; ++kk) {
            #pragma unroll
            for (int i = 0; i < 6; ++i) af[i] = MFMA16(za[kk], WfB[i][kk], af[i]);
        }
        #pragma unroll
        for (int sub = 0; sub < 2; ++sub) {
            const float b1r  = sub ? b1r1  : b1r0;
            const float b2r  = sub ? b2r1  : b2r0;
            const float batr = sub ? batr1 : batr0;
            #pragma unroll
            for (int r = 0; r < 4; ++r) {
                const float E1 = ex2(__builtin_fmaf(af[0+sub][r], K2, b1r));
                const float E2 = ex2(__builtin_fmaf(af[2+sub][r], K2, b2r));
                const float E3 = ex2(__builtin_fmaf(af[4+sub][r], K1, batr));
                const float p1_ = E1 + 1.f;
                const float p2_ = E2 + 1.f;
                const float p3_ = E3 + 1.f;
                const float num = __builtin_fmaf(E3, p1_, p2_);
                const float hv  = __builtin_fmaf(-2.f*num, rcpf_(p1_*p2_*p3_), 1.f);
                const int row = (lg<<2) + r;
                hbuf[(row*LAT + (wv<<5) + (sub<<4) + l15) ^ ((row&7)<<3)] = (_Float16)hv;
            }
        }
        if (t > 0 && wv < 4) {
            f32x4 ao = fz;
            #pragma unroll
            for (int kk = 0; kk < 4; ++kk) {
                const half8 aa = *(const half8*)&dbuf[(l15*HLF + kk*32 + krow) ^ ((l15&7)<<3)];
                ao = MFMA16(aa, *(const half8*)(wp2p + kk*512), ao);
            }
            #pragma unroll
            for (int r = 0; r < 4; ++r)
                obase[(size_t)r*(T_*OUTD) + (size_t)(t-1)*OUTD] = ao[r] + bp2r;
        }
        __syncthreads();
    }
    {
        #pragma unroll
        for (int kk = 0; kk < 8; ++kk)
            ha[kk] = *(const half8*)&hbuf[(l15*LAT + kk*32 + krow) ^ ((l15&7)<<3)];
        f32x4 ap0 = fz, ap1 = fz;
        #pragma unroll
        for (int kk = 0; kk < 8; kk += 2) {
            ap0 = MFMA16(ha[kk],   *(const half8*)(wp1p +  kk   *512), ap0);
            ap1 = MFMA16(ha[kk+1], *(const half8*)(wp1p + (kk+1)*512), ap1);
        }
        const f32x4 ap = ap0 + ap1;
        #pragma unroll
        for (int r = 0; r < 4; ++r) {
            const float v  = ap[r] + bp1a;
            const float E  = ex2(__builtin_fmaf(ap[r], K1, bp1k));
            const float sg = rcpf_(E + 1.f);
            const float hd = __builtin_fmaf(-v, sg, v);
            const int row = (lg<<2) + r;
            dbuf[(row*HLF + cz) ^ ((row&7)<<3)] = (_Float16)hd;
        }
        __syncthreads();
        if (wv < 4) {
            f32x4 ao = fz;
            #pragma unroll
            for (int kk = 0; kk < 4; ++kk) {
                const half8 aa = *(const half8*)&dbuf[(l15*HLF + kk*32 + krow) ^ ((l15&7)<<3)];
                ao = MFMA16(aa, *(const half8*)(wp2p + kk*512), ao);
            }
            #pragma unroll
            for (int r = 0; r < 4; ++r)
                obase[(size_t)r*(T_*OUTD) + (size_t)(T_-1)*OUTD] = ao[r] + bp2r;
        }
    }
}

extern "C" void kernel_launch(void* const* d_in, const int* in_sizes, int n_in,
                              void* d_out, int out_size, void* d_ws, size_t ws_size,
                              hipStream_t stream) {
    (void)in_sizes; (void)n_in; (void)out_size;
    const float* x   = (const float*)d_in[0];
    const float* Wb  = (const float*)d_in[1];
    const float* bb  = (const float*)d_in[2];
    const float* W1  = (const float*)d_in[3];
    const float* b1  = (const float*)d_in[4];
    const float* W2  = (const float*)d_in[5];
    const float* b2  = (const float*)d_in[6];
    const float* Wa  = (const float*)d_in[7];
    const float* ba  = (const float*)d_in[8];
    const float* Wtb = (const float*)d_in[9];
    const float* btb = (const float*)d_in[10];
    const float* Wp1 = (const float*)d_in[11];
    const float* bp1 = (const float*)d_in[12];
    const float* Wp2 = (const float*)d_in[13];
    const float* bp2 = (const float*)d_in[14];

    const size_t seq_bytes = (size_t)256 * T_ * LAT * sizeof(_Float16);   // 67MB
    const size_t xh_bytes  = (size_t)256 * T_ * IND * sizeof(_Float16);   // 16.8MB

    if (ws_size >= seq_bytes + xh_bytes) {
        _Float16* seq = (_Float16*)d_ws;
        _Float16* xh  = (_Float16*)((char*)d_ws + seq_bytes);
        x2h<<<dim3(2048), dim3(256), 0, stream>>>(x, xh);
        cfc_scan4<true><<<dim3(16), dim3(512), 0, stream>>>(
            x, xh, Wb, bb, W1, b1, W2, b2, Wa, ba, Wtb, btb, seq);
        cfc_proj<<<dim3(2048), dim3(256), 0, stream>>>(
            seq, Wp1, bp1, Wp2, bp2, (float*)d_out);
    } else if (ws_size >= seq_bytes) {
        _Float16* seq = (_Float16*)d_ws;
        cfc_scan4<false><<<dim3(16), dim3(512), 0, stream>>>(
            x, nullptr, Wb, bb, W1, b1, W2, b2, Wa, ba, Wtb, btb, seq);
        cfc_proj<<<dim3(2048), dim3(256), 0, stream>>>(
            seq, Wp1, bp1, Wp2, bp2, (float*)d_out);
    } else {
        cfc_fused_fb<<<dim3(16), dim3(512), 0, stream>>>(
            x, Wb, bb, W1, b1, W2, b2, Wa, ba, Wtb, btb, Wp1, bp1, Wp2, bp2,
            (float*)d_out);
    }
}

// Round 9
// 641.687 us; speedup vs baseline: 1.6954x; 1.1708x over previous
//
#include <hip/hip_runtime.h>

// CfC, round 9: 32 blocks x 8 batch rows (trans work halved per CU).
//  A-rows loaded duplicated (l15&7) -> MFMA output rows 8-15 are copies of
//  rows 0-7 -> lanes lg>=2 already hold copies of valid values -> pointwise
//  split across all 64 lanes with cndmask selects, no shuffles:
//    lg<2 lanes process r=0,1 ; lg>=2 process r=2,3 (their duplicates).
//  Per-thread per-step: z-trans 4 (was 8), blend-trans 16 (was 32).
//  Everything else = R7: XH pre-convert, lgkm-only barriers, 2 barriers/step,
//  seq stored from hv in phase B. cfc_proj / fallback unchanged.

#define T_   512
#define IND  64
#define LAT  256
#define BBD  128
#define OUTD 64
#define HLF  128

typedef _Float16 half8 __attribute__((ext_vector_type(8)));
typedef float    f32x4 __attribute__((ext_vector_type(4)));
typedef float    f4    __attribute__((ext_vector_type(4)));

#define MFMA16(a,b,c) __builtin_amdgcn_mfma_f32_16x16x32_f16((a),(b),(c),0,0,0)

__device__ __forceinline__ float ex2(float x)   { return __builtin_amdgcn_exp2f(x); }
__device__ __forceinline__ float rcpf_(float x) { return __builtin_amdgcn_rcpf(x); }
__device__ __forceinline__ void barrier_lds() {
    asm volatile("s_waitcnt lgkmcnt(0)\n\ts_barrier" ::: "memory");
}

// ====================== K0: x -> fp16 pre-convert ===========================
__global__ void __launch_bounds__(256) x2h(const float* __restrict__ x,
                                           _Float16* __restrict__ xh) {
    const size_t i = ((size_t)blockIdx.x * 256 + threadIdx.x) * 16;
    f4 a = *(const f4*)(x + i);
    f4 b = *(const f4*)(x + i + 4);
    f4 c = *(const f4*)(x + i + 8);
    f4 d = *(const f4*)(x + i + 12);
    half8 lo, hi;
    #pragma unroll
    for (int e = 0; e < 4; ++e) {
        lo[e] = (_Float16)a[e]; lo[e+4] = (_Float16)b[e];
        hi[e] = (_Float16)c[e]; hi[e+4] = (_Float16)d[e];
    }
    *(half8*)(xh + i)     = lo;
    *(half8*)(xh + i + 8) = hi;
}

// ============================ K1: recurrence scan ============================
// 32 blocks x 512 thr; block owns 8 batch rows.
template<bool XH>
__global__ void __launch_bounds__(512, 2) cfc_scan5(
    const float* __restrict__ x, const _Float16* __restrict__ xh,
    const float* __restrict__ Wb,  const float* __restrict__ bb,
    const float* __restrict__ W1,  const float* __restrict__ b1,
    const float* __restrict__ W2,  const float* __restrict__ b2,
    const float* __restrict__ Wa,  const float* __restrict__ ba,
    const float* __restrict__ Wtb, const float* __restrict__ btb,
    _Float16* __restrict__ seq)
{
    const int tid  = threadIdx.x;
    const int wv   = tid >> 6;
    const int lane = tid & 63;
    const int l15  = lane & 15;
    const int lg   = lane >> 4;     // 0..3
    const int krow = lg << 3;
    const int b0   = blockIdx.x << 3;     // 8 rows/block
    const int rl   = l15 & 7;             // duplicated A-row for loads

    // pointwise ownership: lanes lg<2 take r=0,1 ; lg>=2 take r=2,3 (copies)
    const int rsel  = lg >> 1;                        // 0 or 1
    const int rbase = ((lg & 1) << 2) + (rsel << 1);  // rows rbase, rbase+1

    __shared__ __align__(16) _Float16 hbuf[8*LAT];    // 4KB
    __shared__ __align__(16) _Float16 zbuf[8*BBD];    // 2KB

    half8 WbB[10];
    {
        const int col = (wv<<4) + l15;
        #pragma unroll
        for (int kk = 0; kk < 10; ++kk) {
            half8 v;
            #pragma unroll
            for (int e = 0; e < 8; ++e)
                v[e] = (_Float16)Wb[(kk*32 + krow + e)*BBD + col];
            WbB[kk] = v;
        }
    }
    half8 WfB[6][4];   // 0,1=W1 2,3=W2 4,5=Wa+Wtb ; 1.7159 folded
    #pragma unroll
    for (int t6 = 0; t6 < 6; ++t6) {
        const int m   = t6 >> 1;
        const int col = (wv<<5) + ((t6&1)<<4) + l15;
        const float* Wm = (m==0) ? W1 : ((m==1) ? W2 : Wa);
        #pragma unroll
        for (int kk = 0; kk < 4; ++kk) {
            half8 v;
            #pragma unroll
            for (int e = 0; e < 8; ++e) {
                const int k = kk*32 + krow + e;
                float f = Wm[k*LAT + col];
                if (m == 2) f += Wtb[k*LAT + col];
                v[e] = (_Float16)(1.7159f * f);
            }
            WfB[t6][kk] = v;
        }
    }

    const float K1 = 1.4426950408889634f;
    const float K2 = 2.8853900817779268f;
    const float KZ = 1.9216698144680396f;
    const int cz  = (wv<<4) + l15;
    const int cf0 = (wv<<5) + l15;
    const int cf1 = cf0 + 16;
    const float bbr   = bb[cz] * KZ;
    const float b1r0  = b1[cf0]*K2,  b1r1  = b1[cf1]*K2;
    const float b2r0  = b2[cf0]*K2,  b2r1  = b2[cf1]*K2;
    const float batr0 = (ba[cf0]+btb[cf0])*K1, batr1 = (ba[cf1]+btb[cf1])*K1;

    // x pointers / prefetch (duplicated rows)
    const float*    xrow  = x  + (size_t)(b0 + rl) * (T_*IND);
    const _Float16* xhrow = xh + (size_t)(b0 + rl) * (T_*IND);
    f4 xq[4];
    half8 xn0, xn1;
    if (XH) {
        xn0 = *(const half8*)(xhrow + krow);
        xn1 = *(const half8*)(xhrow + 32 + krow);
    } else {
        #pragma unroll
        for (int q = 0; q < 4; ++q)
            xq[q] = *(const f4*)(xrow + ((q>>1)*32 + krow + (q&1)*4));
    }

    // pre-zero hbuf (h0 = 0): 4KB by 512 threads x 8B
    ((unsigned long long*)hbuf)[tid] = 0ull;
    barrier_lds();

    const f32x4 fz = {0.f, 0.f, 0.f, 0.f};
    // seq store bases for this thread's two rows (rbase, rbase+1)
    _Float16* const sq0 = seq + (size_t)(b0 + rbase)     * (T_*LAT) + (wv<<5) + l15;
    _Float16* const sq1 = seq + (size_t)(b0 + rbase + 1) * (T_*LAT) + (wv<<5) + l15;

    #pragma unroll 1
    for (int t = 0; t < T_; ++t) {
        // ============================ PHASE A ============================
        half8 ha[8];
        #pragma unroll
        for (int kk = 0; kk < 8; ++kk)
            ha[kk] = *(const half8*)&hbuf[(rl*LAT + kk*32 + krow) ^ (rl<<3)];

        half8 xa0, xa1;
        if (XH) {
            xa0 = xn0; xa1 = xn1;
            const int tn = (t < T_-1) ? (t+1) : t;
            xn0 = *(const half8*)(xhrow + tn*IND + krow);
            xn1 = *(const half8*)(xhrow + tn*IND + 32 + krow);
        } else {
            #pragma unroll
            for (int e = 0; e < 4; ++e) {
                xa0[e]   = (_Float16)xq[0][e];
                xa0[e+4] = (_Float16)xq[1][e];
                xa1[e]   = (_Float16)xq[2][e];
                xa1[e+4] = (_Float16)xq[3][e];
            }
            const int tn = (t < T_-1) ? (t+1) : t;
            const float* p = xrow + tn*IND + krow;
            #pragma unroll
            for (int q = 0; q < 4; ++q)
                xq[q] = *(const f4*)(p + (q>>1)*32 + (q&1)*4);
        }

        // GEMM_h: 3 parallel chains
        f32x4 azx = MFMA16(xa0, WbB[0], fz);
        azx = MFMA16(xa1, WbB[1], azx);
        f32x4 az0 = MFMA16(ha[0], WbB[2], fz);
        f32x4 az1 = MFMA16(ha[1], WbB[3], fz);
        #pragma unroll
        for (int kk = 2; kk < 8; kk += 2) {
            az0 = MFMA16(ha[kk],   WbB[kk+2], az0);
            az1 = MFMA16(ha[kk+1], WbB[kk+3], az1);
        }
        const f32x4 az = (azx + az0) + az1;

        // z-trans: 2 values per thread (rows rbase, rbase+1)
        {
            const float v0 = rsel ? az[2] : az[0];
            const float v1 = rsel ? az[3] : az[1];
            {
                const float E = ex2(__builtin_fmaf(v0, KZ, bbr));
                const float z = __builtin_fmaf(-2.f, rcpf_(E + 1.f), 1.f);
                zbuf[(rbase*BBD + cz) ^ (rbase<<3)] = (_Float16)z;
            }
            {
                const float E = ex2(__builtin_fmaf(v1, KZ, bbr));
                const float z = __builtin_fmaf(-2.f, rcpf_(E + 1.f), 1.f);
                zbuf[((rbase+1)*BBD + cz) ^ ((rbase+1)<<3)] = (_Float16)z;
            }
        }
        barrier_lds();   // bar 1: zbuf ready

        // ============================ PHASE B ============================
        half8 za[4];
        #pragma unroll
        for (int kk = 0; kk < 4; ++kk)
            za[kk] = *(const half8*)&zbuf[(rl*BBD + kk*32 + krow) ^ (rl<<3)];

        // group 0: tiles 0,2,4 ; group 1: tiles 1,3,5
        f32x4 af0 = fz, af2 = fz, af4 = fz;
        #pragma unroll
        for (int kk = 0; kk < 4; ++kk) {
            af0 = MFMA16(za[kk], WfB[0][kk], af0);
            af2 = MFMA16(za[kk], WfB[2][kk], af2);
            af4 = MFMA16(za[kk], WfB[4][kk], af4);
        }
        f32x4 af1 = fz, af3 = fz, af5 = fz;
        #pragma unroll
        for (int kk = 0; kk < 4; ++kk) {
            af1 = MFMA16(za[kk], WfB[1][kk], af1);
            af3 = MFMA16(za[kk], WfB[3][kk], af3);
            af5 = MFMA16(za[kk], WfB[5][kk], af5);
        }

        // blend: 2 rows x 2 sub-cols per thread (valid rows only)
        #pragma unroll
        for (int i = 0; i < 2; ++i) {
            const int   row = rbase + i;
            _Float16* const sp = (i ? sq1 : sq0) + (size_t)t * LAT;
            // sub0 (col cf0) from af0/af2/af4
            {
                const float a1v = rsel ? af0[2+i] : af0[i];
                const float a2v = rsel ? af2[2+i] : af2[i];
                const float a3v = rsel ? af4[2+i] : af4[i];
                const float E1 = ex2(__builtin_fmaf(a1v, K2, b1r0));
                const float E2 = ex2(__builtin_fmaf(a2v, K2, b2r0));
                const float E3 = ex2(__builtin_fmaf(a3v, K1, batr0));
                const float p1_ = E1 + 1.f;
                const float p2_ = E2 + 1.f;
                const float p3_ = E3 + 1.f;
                const float num = __builtin_fmaf(E3, p1_, p2_);
                const float hv  = __builtin_fmaf(-2.f*num, rcpf_(p1_*p2_*p3_), 1.f);
                const _Float16 hh = (_Float16)hv;
                hbuf[(row*LAT + (wv<<5) + l15) ^ (row<<3)] = hh;
                sp[0] = hh;
            }
            // sub1 (col cf1) from af1/af3/af5
            {
                const float a1v = rsel ? af1[2+i] : af1[i];
                const float a2v = rsel ? af3[2+i] : af3[i];
                const float a3v = rsel ? af5[2+i] : af5[i];
                const float E1 = ex2(__builtin_fmaf(a1v, K2, b1r1));
                const float E2 = ex2(__builtin_fmaf(a2v, K2, b2r1));
                const float E3 = ex2(__builtin_fmaf(a3v, K1, batr1));
                const float p1_ = E1 + 1.f;
                const float p2_ = E2 + 1.f;
                const float p3_ = E3 + 1.f;
                const float num = __builtin_fmaf(E3, p1_, p2_);
                const float hv  = __builtin_fmaf(-2.f*num, rcpf_(p1_*p2_*p3_), 1.f);
                const _Float16 hh = (_Float16)hv;
                hbuf[(row*LAT + (wv<<5) + 16 + l15) ^ (row<<3)] = hh;
                sp[16] = hh;
            }
        }
        barrier_lds();   // bar 2: hbuf ready for t+1
    }
}

// ============================ K2: projection =================================
__global__ void __launch_bounds__(256, 2) cfc_proj(
    const _Float16* __restrict__ seq,
    const float* __restrict__ Wp1, const float* __restrict__ bp1,
    const float* __restrict__ Wp2, const float* __restrict__ bp2,
    float* __restrict__ out)
{
    const int tid  = threadIdx.x;
    const int wv   = tid >> 6;      // 0..3
    const int lane = tid & 63;
    const int l15  = lane & 15;
    const int lg   = lane >> 4;
    const int krow = lg << 3;

    __shared__ __align__(16) _Float16 wp1l[64*512];      // 64KB
    __shared__ __align__(16) _Float16 wp2l[16*512];      // 16KB
    __shared__ __align__(16) _Float16 dbuf[4][16*HLF];   // 16KB

    #pragma unroll
    for (int f = 0; f < 16; ++f) {
        const int g = wv*16 + f, tt = g >> 3, kk = g & 7;
        half8 v;
        #pragma unroll
        for (int e = 0; e < 8; ++e)
            v[e] = (_Float16)Wp1[(kk*32 + krow + e)*HLF + (tt<<4) + l15];
        *(half8*)&wp1l[g*512 + (lane<<3)] = v;
    }
    #pragma unroll
    for (int f = 0; f < 4; ++f) {
        const int g = wv*4 + f, tt = g >> 2, kk = g & 3;
        half8 v;
        #pragma unroll
        for (int e = 0; e < 8; ++e)
            v[e] = (_Float16)Wp2[(kk*32 + krow + e)*OUTD + (tt<<4) + l15];
        *(half8*)&wp2l[g*512 + (lane<<3)] = v;
    }

    const float K1 = 1.4426950408889634f;
    float bp1v[8], bp1kv[8];
    #pragma unroll
    for (int tt = 0; tt < 8; ++tt) {
        bp1v[tt]  = bp1[(tt<<4) + l15];
        bp1kv[tt] = bp1v[tt] * K1;
    }
    float bp2v[4];
    #pragma unroll
    for (int tt = 0; tt < 4; ++tt) bp2v[tt] = bp2[(tt<<4) + l15];

    __syncthreads();

    const int m0 = (blockIdx.x*4 + wv) << 4;
    const f32x4 fz = {0.f, 0.f, 0.f, 0.f};

    half8 ha[8];
    {
        const _Float16* ap = seq + (size_t)(m0 + l15)*LAT + krow;
        #pragma unroll
        for (int kk = 0; kk < 8; ++kk)
            ha[kk] = *(const half8*)(ap + kk*32);
    }

    #pragma unroll
    for (int tt = 0; tt < 8; ++tt) {
        f32x4 a0 = fz, a1 = fz;
        #pragma unroll
        for (int kk = 0; kk < 8; kk += 2) {
            a0 = MFMA16(ha[kk],   *(const half8*)&wp1l[((tt<<3)+kk  )*512 + (lane<<3)], a0);
            a1 = MFMA16(ha[kk+1], *(const half8*)&wp1l[((tt<<3)+kk+1)*512 + (lane<<3)], a1);
        }
        const f32x4 ap = a0 + a1;
        #pragma unroll
        for (int r = 0; r < 4; ++r) {
            const float v  = ap[r] + bp1v[tt];
            const float E  = ex2(__builtin_fmaf(ap[r], K1, bp1kv[tt]));
            const float sg = rcpf_(E + 1.f);
            const float hd = __builtin_fmaf(-v, sg, v);
            const int row = (lg<<2) + r;
            dbuf[wv][(row*HLF + (tt<<4) + l15) ^ ((row&7)<<3)] = (_Float16)hd;
        }
    }

    half8 pa[4];
    #pragma unroll
    for (int kk = 0; kk < 4; ++kk)
        pa[kk] = *(const half8*)&dbuf[wv][(l15*HLF + kk*32 + krow) ^ ((l15&7)<<3)];
    #pragma unroll
    for (int tt = 0; tt < 4; ++tt) {
        f32x4 ao = fz;
        #pragma unroll
        for (int kk = 0; kk < 4; ++kk)
            ao = MFMA16(pa[kk], *(const half8*)&wp2l[((tt<<2)+kk)*512 + (lane<<3)], ao);
        #pragma unroll
        for (int r = 0; r < 4; ++r)
            out[(size_t)(m0 + (lg<<2) + r)*OUTD + (tt<<4) + l15] = ao[r] + bp2v[tt];
    }
}

// ==================== fallback: R3 fused kernel (ws too small) ===============
__global__ void __launch_bounds__(512, 2) cfc_fused_fb(
    const float* __restrict__ x,
    const float* __restrict__ Wb,  const float* __restrict__ bb,
    const float* __restrict__ W1,  const float* __restrict__ b1,
    const float* __restrict__ W2,  const float* __restrict__ b2,
    const float* __restrict__ Wa,  const float* __restrict__ ba,
    const float* __restrict__ Wtb, const float* __restrict__ btb,
    const float* __restrict__ Wp1, const float* __restrict__ bp1,
    const float* __restrict__ Wp2, const float* __restrict__ bp2,
    float* __restrict__ out)
{
    const int tid  = threadIdx.x;
    const int wv   = tid >> 6;
    const int lane = tid & 63;
    const int l15  = lane & 15;
    const int lg   = lane >> 4;
    const int krow = lg << 3;
    const int b0   = blockIdx.x << 4;

    __shared__ __align__(16) _Float16 hbuf[16*LAT];
    __shared__ __align__(16) _Float16 zbuf[16*BBD];
    __shared__ __align__(16) _Float16 dbuf[16*HLF];
    __shared__ __align__(16) _Float16 wp1l[64*512];
    __shared__ __align__(16) _Float16 wp2l[16*512];

    half8 WbB[10];
    {
        const int col = (wv<<4) + l15;
        #pragma unroll
        for (int kk = 0; kk < 10; ++kk) {
            half8 v;
            #pragma unroll
            for (int e = 0; e < 8; ++e)
                v[e] = (_Float16)Wb[(kk*32 + krow + e)*BBD + col];
            WbB[kk] = v;
        }
    }
    half8 WfB[6][4];
    #pragma unroll
    for (int t6 = 0; t6 < 6; ++t6) {
        const int m   = t6 >> 1;
        const int col = (wv<<5) + ((t6&1)<<4) + l15;
        const float* Wm = (m==0) ? W1 : ((m==1) ? W2 : Wa);
        #pragma unroll
        for (int kk = 0; kk < 4; ++kk) {
            half8 v;
            #pragma unroll
            for (int e = 0; e < 8; ++e) {
                const int k = kk*32 + krow + e;
                float f = Wm[k*LAT + col];
                if (m == 2) f += Wtb[k*LAT + col];
                v[e] = (_Float16)(1.7159f * f);
            }
            WfB[t6][kk] = v;
        }
    }
    {
        const int col = (wv<<4) + l15;
        #pragma unroll
        for (int kk = 0; kk < 8; ++kk) {
            half8 v;
            #pragma unroll
            for (int e = 0; e < 8; ++e)
                v[e] = (_Float16)Wp1[(kk*32 + krow + e)*HLF + col];
            *(half8*)&wp1l[((wv<<3) + kk)*512 + (lane<<3)] = v;
        }
        if (wv < 4) {
            #pragma unroll
            for (int kk = 0; kk < 4; ++kk) {
                half8 v;
                #pragma unroll
                for (int e = 0; e < 8; ++e)
                    v[e] = (_Float16)Wp2[(kk*32 + krow + e)*OUTD + col];
                *(half8*)&wp2l[((wv<<2) + kk)*512 + (lane<<3)] = v;
            }
        }
    }
    const _Float16* const wp1p = &wp1l[(wv<<3)*512 + (lane<<3)];
    const _Float16* const wp2p = &wp2l[(wv<<2)*512 + (lane<<3)];

    const float K1 = 1.4426950408889634f;
    const float K2 = 2.8853900817779268f;
    const float KZ = 1.9216698144680396f;
    const int cz  = (wv<<4) + l15;
    const int cf0 = (wv<<5) + l15;
    const int cf1 = cf0 + 16;
    const float bbr   = bb[cz] * KZ;
    const float b1r0  = b1[cf0]*K2,  b1r1  = b1[cf1]*K2;
    const float b2r0  = b2[cf0]*K2,  b2r1  = b2[cf1]*K2;
    const float batr0 = (ba[cf0]+btb[cf0])*K1, batr1 = (ba[cf1]+btb[cf1])*K1;
    const float bp1a  = bp1[cz];
    const float bp1k  = bp1a * K1;
    const float bp2r  = (wv < 4) ? bp2[cz] : 0.f;

    __syncthreads();

    const float* xrow = x + (size_t)(b0 + l15) * (T_*IND);
    f4 xq[4];
    #pragma unroll
    for (int q = 0; q < 4; ++q)
        xq[q] = *(const f4*)(xrow + ((q>>1)*32 + krow + (q&1)*4));

    half8 ha[8];
    {
        half8 hz;
        #pragma unroll
        for (int e = 0; e < 8; ++e) hz[e] = (_Float16)0.f;
        #pragma unroll
        for (int i = 0; i < 8; ++i) ha[i] = hz;
    }
    const f32x4 fz = {0.f, 0.f, 0.f, 0.f};
    float* const obase = out + (size_t)(b0 + (lg<<2)) * (T_*OUTD) + (wv<<4) + l15;

    #pragma unroll 1
    for (int t = 0; t < T_; ++t) {
        if (t > 0) {
            #pragma unroll
            for (int kk = 0; kk < 8; ++kk)
                ha[kk] = *(const half8*)&hbuf[(l15*LAT + kk*32 + krow) ^ ((l15&7)<<3)];
        }
        half8 xa0, xa1;
        #pragma unroll
        for (int e = 0; e < 4; ++e) {
            xa0[e]   = (_Float16)xq[0][e];
            xa0[e+4] = (_Float16)xq[1][e];
            xa1[e]   = (_Float16)xq[2][e];
            xa1[e+4] = (_Float16)xq[3][e];
        }
        {
            const int tn = (t < T_-1) ? (t+1) : t;
            const float* p = xrow + tn*IND + krow;
            #pragma unroll
            for (int q = 0; q < 4; ++q)
                xq[q] = *(const f4*)(p + (q>>1)*32 + (q&1)*4);
        }
        f32x4 az0 = MFMA16(xa0, WbB[0], fz);
        f32x4 az1 = MFMA16(xa1, WbB[1], fz);
        #pragma unroll
        for (int kk = 0; kk < 8; kk += 2) {
            az0 = MFMA16(ha[kk],   WbB[kk+2], az0);
            az1 = MFMA16(ha[kk+1], WbB[kk+3], az1);
        }
        const f32x4 az = az0 + az1;
        #pragma unroll
        for (int r = 0; r < 4; ++r) {
            const float E = ex2(__builtin_fmaf(az[r], KZ, bbr));
            const float z = __builtin_fmaf(-2.f, rcpf_(E + 1.f), 1.f);
            const int row = (lg<<2) + r;
            zbuf[(row*BBD + cz) ^ ((row&7)<<3)] = (_Float16)z;
        }
        if (t > 0) {
            f32x4 ap0 = fz, ap1 = fz;
            #pragma unroll
            for (int kk = 0; kk < 8; kk += 2) {
                ap0 = MFMA16(ha[kk],   *(const half8*)(wp1p +  kk   *512), ap0);
                ap1 = MFMA16(ha[kk+1], *(const half8*)(wp1p + (kk+1)*512), ap1);
            }
            const f32x4 ap = ap0 + ap1;
            #pragma unroll
            for (int r = 0; r < 4; ++r) {
                const float v  = ap[r] + bp1a;
                const float E  = ex2(__builtin_fmaf(ap[r], K1, bp1k));
                const float sg = rcpf_(E + 1.f);
                const float hd = __builtin_fmaf(-v, sg, v);
                const int row = (lg<<2) + r;
                dbuf[(row*HLF + cz) ^ ((row&7)<<3)] = (_Float16)hd;
            }
        }
        __syncthreads();

        half8 za[4];
        #pragma unroll
        for (int kk = 0; kk < 4; ++kk)
            za[kk] = *(const half8*)&zbuf[(l15*BBD + kk*32 + krow) ^ ((l15&7)<<3)];
        f32x4 af[6];
        #pragma unroll
        for (int i = 0; i < 6; ++i) af[i] = fz;
        #pragma unroll
        for (int kk = 0; kk < 4; ++kk) {
            #pragma unroll
            for (int i = 0; i < 6; ++i) af[i] = MFMA16(za[kk], WfB[i][kk], af[i]);
        }
        #pragma unroll
        for (int sub = 0; sub < 2; ++sub) {
            const float b1r  = sub ? b1r1  : b1r0;
            const float b2r  = sub ? b2r1  : b2r0;
            const float batr = sub ? batr1 : batr0;
            #pragma unroll
            for (int r = 0; r < 4; ++r) {
                const float E1 = ex2(__builtin_fmaf(af[0+sub][r], K2, b1r));
                const float E2 = ex2(__builtin_fmaf(af[2+sub][r], K2, b2r));
                const float E3 = ex2(__builtin_fmaf(af[4+sub][r], K1, batr));
                const float p1_ = E1 + 1.f;
                const float p2_ = E2 + 1.f;
                const float p3_ = E3 + 1.f;
                const float num = __builtin_fmaf(E3, p1_, p2_);
                const float hv  = __builtin_fmaf(-2.f*num, rcpf_(p1_*p2_*p3_), 1.f);
                const int row = (lg<<2) + r;
                hbuf[(row*LAT + (wv<<5) + (sub<<4) + l15) ^ ((row&7)<<3)] = (_Float16)hv;
            }
        }
        if (t > 0 && wv < 4) {
            f32x4 ao = fz;
            #pragma unroll
            for (int kk = 0; kk < 4; ++kk) {
                const half8 aa = *(const half8*)&dbuf[(l15*HLF + kk*32 + krow) ^ ((l15&7)<<3)];
                ao = MFMA16(aa, *(const half8*)(wp2p + kk*512), ao);
            }
            #pragma unroll
            for (int r = 0; r < 4; ++r)
                obase[(size_t)r*(T_*OUTD) + (size_t)(t-1)*OUTD] = ao[r] + bp2r;
        }
        __syncthreads();
    }
    {
        #pragma unroll
        for (int kk = 0; kk < 8; ++kk)
            ha[kk] = *(const half8*)&hbuf[(l15*LAT + kk*32 + krow) ^ ((l15&7)<<3)];
        f32x4 ap0 = fz, ap1 = fz;
        #pragma unroll
        for (int kk = 0; kk < 8; kk += 2) {
            ap0 = MFMA16(ha[kk],   *(const half8*)(wp1p +  kk   *512), ap0);
            ap1 = MFMA16(ha[kk+1], *(const half8*)(wp1p + (kk+1)*512), ap1);
        }
        const f32x4 ap = ap0 + ap1;
        #pragma unroll
        for (int r = 0; r < 4; ++r) {
            const float v  = ap[r] + bp1a;
            const float E  = ex2(__builtin_fmaf(ap[r], K1, bp1k));
            const float sg = rcpf_(E + 1.f);
            const float hd = __builtin_fmaf(-v, sg, v);
            const int row = (lg<<2) + r;
            dbuf[(row*HLF + cz) ^ ((row&7)<<3)] = (_Float16)hd;
        }
        __syncthreads();
        if (wv < 4) {
            f32x4 ao = fz;
            #pragma unroll
            for (int kk = 0; kk < 4; ++kk) {
                const half8 aa = *(const half8*)&dbuf[(l15*HLF + kk*32 + krow) ^ ((l15&7)<<3)];
                ao = MFMA16(aa, *(const half8*)(wp2p + kk*512), ao);
            }
            #pragma unroll
            for (int r = 0; r < 4; ++r)
                obase[(size_t)r*(T_*OUTD) + (size_t)(T_-1)*OUTD] = ao[r] + bp2r;
        }
    }
}

extern "C" void kernel_launch(void* const* d_in, const int* in_sizes, int n_in,
                              void* d_out, int out_size, void* d_ws, size_t ws_size,
                              hipStream_t stream) {
    (void)in_sizes; (void)n_in; (void)out_size;
    const float* x   = (const float*)d_in[0];
    const float* Wb  = (const float*)d_in[1];
    const float* bb  = (const float*)d_in[2];
    const float* W1  = (const float*)d_in[3];
    const float* b1  = (const float*)d_in[4];
    const float* W2  = (const float*)d_in[5];
    const float* b2  = (const float*)d_in[6];
    const float* Wa  = (const float*)d_in[7];
    const float* ba  = (const float*)d_in[8];
    const float* Wtb = (const float*)d_in[9];
    const float* btb = (const float*)d_in[10];
    const float* Wp1 = (const float*)d_in[11];
    const float* bp1 = (const float*)d_in[12];
    const float* Wp2 = (const float*)d_in[13];
    const float* bp2 = (const float*)d_in[14];

    const size_t seq_bytes = (size_t)256 * T_ * LAT * sizeof(_Float16);   // 67MB
    const size_t xh_bytes  = (size_t)256 * T_ * IND * sizeof(_Float16);   // 16.8MB

    if (ws_size >= seq_bytes + xh_bytes) {
        _Float16* seq = (_Float16*)d_ws;
        _Float16* xh  = (_Float16*)((char*)d_ws + seq_bytes);
        x2h<<<dim3(2048), dim3(256), 0, stream>>>(x, xh);
        cfc_scan5<true><<<dim3(32), dim3(512), 0, stream>>>(
            x, xh, Wb, bb, W1, b1, W2, b2, Wa, ba, Wtb, btb, seq);
        cfc_proj<<<dim3(2048), dim3(256), 0, stream>>>(
            seq, Wp1, bp1, Wp2, bp2, (float*)d_out);
    } else if (ws_size >= seq_bytes) {
        _Float16* seq = (_Float16*)d_ws;
        cfc_scan5<false><<<dim3(32), dim3(512), 0, stream>>>(
            x, nullptr, Wb, bb, W1, b1, W2, b2, Wa, ba, Wtb, btb, seq);
        cfc_proj<<<dim3(2048), dim3(256), 0, stream>>>(
            seq, Wp1, bp1, Wp2, bp2, (float*)d_out);
    } else {
        cfc_fused_fb<<<dim3(16), dim3(512), 0, stream>>>(
            x, Wb, bb, W1, b1, W2, b2, Wa, ba, Wtb, btb, Wp1, bp1, Wp2, bp2,
            (float*)d_out);
    }
}

// Round 10
// 529.276 us; speedup vs baseline: 2.0555x; 1.2124x over previous
//
#include <hip/hip_runtime.h>

// CfC, round 10: 64 blocks x 4 batch rows (4x dup) + padded-stride LDS.
//  - 4x row duplication: every lane's acc[r] = valid row r, so lane (lg,l15)
//    owns row lg via 3-cndmask extracts (static indices). Trans/thread: 10.
//  - padded strides (hbuf 272, zbuf 144 elems) instead of XOR swizzle:
//    <=2-way bank aliasing (free) AND ds_read/write offset:N immediate folding
//    (XOR previously forced per-access VALU address math).
//  - otherwise R9 structure: XH fp16 x, lgkm-only barriers, 2 barriers/step,
//    seq stores from hv in phase B. cfc_proj / fallback unchanged.

#define T_   512
#define IND  64
#define LAT  256
#define BBD  128
#define OUTD 64
#define HLF  128
#define HST  272   // hbuf row stride (elems)
#define ZST  144   // zbuf row stride (elems)

typedef _Float16 half8 __attribute__((ext_vector_type(8)));
typedef float    f32x4 __attribute__((ext_vector_type(4)));
typedef float    f4    __attribute__((ext_vector_type(4)));

#define MFMA16(a,b,c) __builtin_amdgcn_mfma_f32_16x16x32_f16((a),(b),(c),0,0,0)

__device__ __forceinline__ float ex2(float x)   { return __builtin_amdgcn_exp2f(x); }
__device__ __forceinline__ float rcpf_(float x) { return __builtin_amdgcn_rcpf(x); }
__device__ __forceinline__ void barrier_lds() {
    asm volatile("s_waitcnt lgkmcnt(0)\n\ts_barrier" ::: "memory");
}
// extract v[lg] with static indices (3 cndmask; no scratch)
__device__ __forceinline__ float sel4(const f32x4 v, bool s0, bool s1) {
    const float lo = s0 ? v[1] : v[0];
    const float hi = s0 ? v[3] : v[2];
    return s1 ? hi : lo;
}

// ====================== K0: x -> fp16 pre-convert ===========================
__global__ void __launch_bounds__(256) x2h(const float* __restrict__ x,
                                           _Float16* __restrict__ xh) {
    const size_t i = ((size_t)blockIdx.x * 256 + threadIdx.x) * 16;
    f4 a = *(const f4*)(x + i);
    f4 b = *(const f4*)(x + i + 4);
    f4 c = *(const f4*)(x + i + 8);
    f4 d = *(const f4*)(x + i + 12);
    half8 lo, hi;
    #pragma unroll
    for (int e = 0; e < 4; ++e) {
        lo[e] = (_Float16)a[e]; lo[e+4] = (_Float16)b[e];
        hi[e] = (_Float16)c[e]; hi[e+4] = (_Float16)d[e];
    }
    *(half8*)(xh + i)     = lo;
    *(half8*)(xh + i + 8) = hi;
}

// ============================ K1: recurrence scan ============================
// 64 blocks x 512 thr; block owns 4 batch rows (4x duplicated in M=16).
template<bool XH>
__global__ void __launch_bounds__(512, 2) cfc_scan6(
    const float* __restrict__ x, const _Float16* __restrict__ xh,
    const float* __restrict__ Wb,  const float* __restrict__ bb,
    const float* __restrict__ W1,  const float* __restrict__ b1,
    const float* __restrict__ W2,  const float* __restrict__ b2,
    const float* __restrict__ Wa,  const float* __restrict__ ba,
    const float* __restrict__ Wtb, const float* __restrict__ btb,
    _Float16* __restrict__ seq)
{
    const int tid  = threadIdx.x;
    const int wv   = tid >> 6;
    const int lane = tid & 63;
    const int l15  = lane & 15;
    const int lg   = lane >> 4;     // 0..3
    const int krow = lg << 3;
    const int b0   = blockIdx.x << 2;     // 4 rows/block
    const int rl   = l15 & 3;             // duplicated data row for A-frags
    const bool s0  = (lg & 1) != 0;       // sel4 flags: pick row lg
    const bool s1  = (lg & 2) != 0;

    __shared__ __align__(16) _Float16 hbuf[4*HST];    // ~2.2KB
    __shared__ __align__(16) _Float16 zbuf[4*ZST];    // ~1.2KB

    half8 WbB[10];
    {
        const int col = (wv<<4) + l15;
        #pragma unroll
        for (int kk = 0; kk < 10; ++kk) {
            half8 v;
            #pragma unroll
            for (int e = 0; e < 8; ++e)
                v[e] = (_Float16)Wb[(kk*32 + krow + e)*BBD + col];
            WbB[kk] = v;
        }
    }
    half8 WfB[6][4];   // 0,1=W1 2,3=W2 4,5=Wa+Wtb ; 1.7159 folded
    #pragma unroll
    for (int t6 = 0; t6 < 6; ++t6) {
        const int m   = t6 >> 1;
        const int col = (wv<<5) + ((t6&1)<<4) + l15;
        const float* Wm = (m==0) ? W1 : ((m==1) ? W2 : Wa);
        #pragma unroll
        for (int kk = 0; kk < 4; ++kk) {
            half8 v;
            #pragma unroll
            for (int e = 0; e < 8; ++e) {
                const int k = kk*32 + krow + e;
                float f = Wm[k*LAT + col];
                if (m == 2) f += Wtb[k*LAT + col];
                v[e] = (_Float16)(1.7159f * f);
            }
            WfB[t6][kk] = v;
        }
    }

    const float K1 = 1.4426950408889634f;
    const float K2 = 2.8853900817779268f;
    const float KZ = 1.9216698144680396f;
    const int cz  = (wv<<4) + l15;          // z col 0..127
    const int cf0 = (wv<<5) + l15;          // blend col sub0
    const int cf1 = cf0 + 16;               // blend col sub1
    const float bbr   = bb[cz] * KZ;
    const float b1r0  = b1[cf0]*K2,  b1r1  = b1[cf1]*K2;
    const float b2r0  = b2[cf0]*K2,  b2r1  = b2[cf1]*K2;
    const float batr0 = (ba[cf0]+btb[cf0])*K1, batr1 = (ba[cf1]+btb[cf1])*K1;

    // x pointers / prefetch (duplicated rows)
    const float*    xrow  = x  + (size_t)(b0 + rl) * (T_*IND);
    const _Float16* xhrow = xh + (size_t)(b0 + rl) * (T_*IND);
    f4 xq[4];
    half8 xn0, xn1;
    if (XH) {
        xn0 = *(const half8*)(xhrow + krow);
        xn1 = *(const half8*)(xhrow + 32 + krow);
    } else {
        #pragma unroll
        for (int q = 0; q < 4; ++q)
            xq[q] = *(const f4*)(xrow + ((q>>1)*32 + krow + (q&1)*4));
    }

    // pre-zero hbuf (h0 = 0): 4*272 elems = 544 dwords
    #pragma unroll
    for (int i = tid; i < 544; i += 512)
        ((unsigned int*)hbuf)[i] = 0u;
    barrier_lds();

    const f32x4 fz = {0.f, 0.f, 0.f, 0.f};
    // invariant LDS bases (offsets fold into ds imm)
    const int haB = rl*HST + krow;          // + kk*32
    const int zaB = rl*ZST + krow;          // + kk*32
    const int zwB = lg*ZST + cz;
    const int hwB = lg*HST + cf0;           // +16 for sub1
    // seq store base: this lane owns row lg, cols cf0/cf1
    _Float16* const sq = seq + (size_t)(b0 + lg) * (T_*LAT) + cf0;

    #pragma unroll 1
    for (int t = 0; t < T_; ++t) {
        // ============================ PHASE A ============================
        half8 ha[8];
        #pragma unroll
        for (int kk = 0; kk < 8; ++kk)
            ha[kk] = *(const half8*)&hbuf[haB + kk*32];

        half8 xa0, xa1;
        if (XH) {
            xa0 = xn0; xa1 = xn1;
            const int tn = (t < T_-1) ? (t+1) : t;
            xn0 = *(const half8*)(xhrow + tn*IND + krow);
            xn1 = *(const half8*)(xhrow + tn*IND + 32 + krow);
        } else {
            #pragma unroll
            for (int e = 0; e < 4; ++e) {
                xa0[e]   = (_Float16)xq[0][e];
                xa0[e+4] = (_Float16)xq[1][e];
                xa1[e]   = (_Float16)xq[2][e];
                xa1[e+4] = (_Float16)xq[3][e];
            }
            const int tn = (t < T_-1) ? (t+1) : t;
            const float* p = xrow + tn*IND + krow;
            #pragma unroll
            for (int q = 0; q < 4; ++q)
                xq[q] = *(const f4*)(p + (q>>1)*32 + (q&1)*4);
        }

        // GEMM_h: 3 parallel chains
        f32x4 azx = MFMA16(xa0, WbB[0], fz);
        azx = MFMA16(xa1, WbB[1], azx);
        f32x4 az0 = MFMA16(ha[0], WbB[2], fz);
        f32x4 az1 = MFMA16(ha[1], WbB[3], fz);
        #pragma unroll
        for (int kk = 2; kk < 8; kk += 2) {
            az0 = MFMA16(ha[kk],   WbB[kk+2], az0);
            az1 = MFMA16(ha[kk+1], WbB[kk+3], az1);
        }
        const f32x4 az = (azx + az0) + az1;

        // z: 1 value per lane (row lg, col cz)
        {
            const float v  = sel4(az, s0, s1);
            const float E  = ex2(__builtin_fmaf(v, KZ, bbr));
            const float zv = __builtin_fmaf(-2.f, rcpf_(E + 1.f), 1.f);
            zbuf[zwB] = (_Float16)zv;
        }
        barrier_lds();   // bar 1: zbuf ready

        // ============================ PHASE B ============================
        half8 za[4];
        #pragma unroll
        for (int kk = 0; kk < 4; ++kk)
            za[kk] = *(const half8*)&zbuf[zaB + kk*32];

        // group 0: tiles 0,2,4 ; group 1: tiles 1,3,5
        f32x4 af0 = fz, af2 = fz, af4 = fz;
        #pragma unroll
        for (int kk = 0; kk < 4; ++kk) {
            af0 = MFMA16(za[kk], WfB[0][kk], af0);
            af2 = MFMA16(za[kk], WfB[2][kk], af2);
            af4 = MFMA16(za[kk], WfB[4][kk], af4);
        }
        f32x4 af1 = fz, af3 = fz, af5 = fz;
        #pragma unroll
        for (int kk = 0; kk < 4; ++kk) {
            af1 = MFMA16(za[kk], WfB[1][kk], af1);
            af3 = MFMA16(za[kk], WfB[3][kk], af3);
            af5 = MFMA16(za[kk], WfB[5][kk], af5);
        }

        _Float16* const sp = sq + (size_t)t * LAT;
        // blend: 2 values per lane (row lg, cols cf0 and cf1)
        {
            const float a1v = sel4(af0, s0, s1);
            const float a2v = sel4(af2, s0, s1);
            const float a3v = sel4(af4, s0, s1);
            const float E1 = ex2(__builtin_fmaf(a1v, K2, b1r0));
            const float E2 = ex2(__builtin_fmaf(a2v, K2, b2r0));
            const float E3 = ex2(__builtin_fmaf(a3v, K1, batr0));
            const float p1_ = E1 + 1.f;
            const float p2_ = E2 + 1.f;
            const float p3_ = E3 + 1.f;
            const float num = __builtin_fmaf(E3, p1_, p2_);
            const float hv  = __builtin_fmaf(-2.f*num, rcpf_(p1_*p2_*p3_), 1.f);
            const _Float16 hh = (_Float16)hv;
            hbuf[hwB] = hh;
            sp[0] = hh;
        }
        {
            const float a1v = sel4(af1, s0, s1);
            const float a2v = sel4(af3, s0, s1);
            const float a3v = sel4(af5, s0, s1);
            const float E1 = ex2(__builtin_fmaf(a1v, K2, b1r1));
            const float E2 = ex2(__builtin_fmaf(a2v, K2, b2r1));
            const float E3 = ex2(__builtin_fmaf(a3v, K1, batr1));
            const float p1_ = E1 + 1.f;
            const float p2_ = E2 + 1.f;
            const float p3_ = E3 + 1.f;
            const float num = __builtin_fmaf(E3, p1_, p2_);
            const float hv  = __builtin_fmaf(-2.f*num, rcpf_(p1_*p2_*p3_), 1.f);
            const _Float16 hh = (_Float16)hv;
            hbuf[hwB + 16] = hh;
            sp[16] = hh;
        }
        barrier_lds();   // bar 2: hbuf ready for t+1
    }
}

// ============================ K2: projection =================================
__global__ void __launch_bounds__(256, 2) cfc_proj(
    const _Float16* __restrict__ seq,
    const float* __restrict__ Wp1, const float* __restrict__ bp1,
    const float* __restrict__ Wp2, const float* __restrict__ bp2,
    float* __restrict__ out)
{
    const int tid  = threadIdx.x;
    const int wv   = tid >> 6;      // 0..3
    const int lane = tid & 63;
    const int l15  = lane & 15;
    const int lg   = lane >> 4;
    const int krow = lg << 3;

    __shared__ __align__(16) _Float16 wp1l[64*512];      // 64KB
    __shared__ __align__(16) _Float16 wp2l[16*512];      // 16KB
    __shared__ __align__(16) _Float16 dbuf[4][16*HLF];   // 16KB

    #pragma unroll
    for (int f = 0; f < 16; ++f) {
        const int g = wv*16 + f, tt = g >> 3, kk = g & 7;
        half8 v;
        #pragma unroll
        for (int e = 0; e < 8; ++e)
            v[e] = (_Float16)Wp1[(kk*32 + krow + e)*HLF + (tt<<4) + l15];
        *(half8*)&wp1l[g*512 + (lane<<3)] = v;
    }
    #pragma unroll
    for (int f = 0; f < 4; ++f) {
        const int g = wv*4 + f, tt = g >> 2, kk = g & 3;
        half8 v;
        #pragma unroll
        for (int e = 0; e < 8; ++e)
            v[e] = (_Float16)Wp2[(kk*32 + krow + e)*OUTD + (tt<<4) + l15];
        *(half8*)&wp2l[g*512 + (lane<<3)] = v;
    }

    const float K1 = 1.4426950408889634f;
    float bp1v[8], bp1kv[8];
    #pragma unroll
    for (int tt = 0; tt < 8; ++tt) {
        bp1v[tt]  = bp1[(tt<<4) + l15];
        bp1kv[tt] = bp1v[tt] * K1;
    }
    float bp2v[4];
    #pragma unroll
    for (int tt = 0; tt < 4; ++tt) bp2v[tt] = bp2[(tt<<4) + l15];

    __syncthreads();

    const int m0 = (blockIdx.x*4 + wv) << 4;
    const f32x4 fz = {0.f, 0.f, 0.f, 0.f};

    half8 ha[8];
    {
        const _Float16* ap = seq + (size_t)(m0 + l15)*LAT + krow;
        #pragma unroll
        for (int kk = 0; kk < 8; ++kk)
            ha[kk] = *(const half8*)(ap + kk*32);
    }

    #pragma unroll
    for (int tt = 0; tt < 8; ++tt) {
        f32x4 a0 = fz, a1 = fz;
        #pragma unroll
        for (int kk = 0; kk < 8; kk += 2) {
            a0 = MFMA16(ha[kk],   *(const half8*)&wp1l[((tt<<3)+kk  )*512 + (lane<<3)], a0);
            a1 = MFMA16(ha[kk+1], *(const half8*)&wp1l[((tt<<3)+kk+1)*512 + (lane<<3)], a1);
        }
        const f32x4 ap = a0 + a1;
        #pragma unroll
        for (int r = 0; r < 4; ++r) {
            const float v  = ap[r] + bp1v[tt];
            const float E  = ex2(__builtin_fmaf(ap[r], K1, bp1kv[tt]));
            const float sg = rcpf_(E + 1.f);
            const float hd = __builtin_fmaf(-v, sg, v);
            const int row = (lg<<2) + r;
            dbuf[wv][(row*HLF + (tt<<4) + l15) ^ ((row&7)<<3)] = (_Float16)hd;
        }
    }

    half8 pa[4];
    #pragma unroll
    for (int kk = 0; kk < 4; ++kk)
        pa[kk] = *(const half8*)&dbuf[wv][(l15*HLF + kk*32 + krow) ^ ((l15&7)<<3)];
    #pragma unroll
    for (int tt = 0; tt < 4; ++tt) {
        f32x4 ao = fz;
        #pragma unroll
        for (int kk = 0; kk < 4; ++kk)
            ao = MFMA16(pa[kk], *(const half8*)&wp2l[((tt<<2)+kk)*512 + (lane<<3)], ao);
        #pragma unroll
        for (int r = 0; r < 4; ++r)
            out[(size_t)(m0 + (lg<<2) + r)*OUTD + (tt<<4) + l15] = ao[r] + bp2v[tt];
    }
}

// ==================== fallback: R3 fused kernel (ws too small) ===============
__global__ void __launch_bounds__(512, 2) cfc_fused_fb(
    const float* __restrict__ x,
    const float* __restrict__ Wb,  const float* __restrict__ bb,
    const float* __restrict__ W1,  const float* __restrict__ b1,
    const float* __restrict__ W2,  const float* __restrict__ b2,
    const float* __restrict__ Wa,  const float* __restrict__ ba,
    const float* __restrict__ Wtb, const float* __restrict__ btb,
    const float* __restrict__ Wp1, const float* __restrict__ bp1,
    const float* __restrict__ Wp2, const float* __restrict__ bp2,
    float* __restrict__ out)
{
    const int tid  = threadIdx.x;
    const int wv   = tid >> 6;
    const int lane = tid & 63;
    const int l15  = lane & 15;
    const int lg   = lane >> 4;
    const int krow = lg << 3;
    const int b0   = blockIdx.x << 4;

    __shared__ __align__(16) _Float16 hbuf[16*LAT];
    __shared__ __align__(16) _Float16 zbuf[16*BBD];
    __shared__ __align__(16) _Float16 dbuf[16*HLF];
    __shared__ __align__(16) _Float16 wp1l[64*512];
    __shared__ __align__(16) _Float16 wp2l[16*512];

    half8 WbB[10];
    {
        const int col = (wv<<4) + l15;
        #pragma unroll
        for (int kk = 0; kk < 10; ++kk) {
            half8 v;
            #pragma unroll
            for (int e = 0; e < 8; ++e)
                v[e] = (_Float16)Wb[(kk*32 + krow + e)*BBD + col];
            WbB[kk] = v;
        }
    }
    half8 WfB[6][4];
    #pragma unroll
    for (int t6 = 0; t6 < 6; ++t6) {
        const int m   = t6 >> 1;
        const int col = (wv<<5) + ((t6&1)<<4) + l15;
        const float* Wm = (m==0) ? W1 : ((m==1) ? W2 : Wa);
        #pragma unroll
        for (int kk = 0; kk < 4; ++kk) {
            half8 v;
            #pragma unroll
            for (int e = 0; e < 8; ++e) {
                const int k = kk*32 + krow + e;
                float f = Wm[k*LAT + col];
                if (m == 2) f += Wtb[k*LAT + col];
                v[e] = (_Float16)(1.7159f * f);
            }
            WfB[t6][kk] = v;
        }
    }
    {
        const int col = (wv<<4) + l15;
        #pragma unroll
        for (int kk = 0; kk < 8; ++kk) {
            half8 v;
            #pragma unroll
            for (int e = 0; e < 8; ++e)
                v[e] = (_Float16)Wp1[(kk*32 + krow + e)*HLF + col];
            *(half8*)&wp1l[((wv<<3) + kk)*512 + (lane<<3)] = v;
        }
        if (wv < 4) {
            #pragma unroll
            for (int kk = 0; kk < 4; ++kk) {
                half8 v;
                #pragma unroll
                for (int e = 0; e < 8; ++e)
                    v[e] = (_Float16)Wp2[(kk*32 + krow + e)*OUTD + col];
                *(half8*)&wp2l[((wv<<2) + kk)*512 + (lane<<3)] = v;
            }
        }
    }
    const _Float16* const wp1p = &wp1l[(wv<<3)*512 + (lane<<3)];
    const _Float16* const wp2p = &wp2l[(wv<<2)*512 + (lane<<3)];

    const float K1 = 1.4426950408889634f;
    const float K2 = 2.8853900817779268f;
    const float KZ = 1.9216698144680396f;
    const int cz  = (wv<<4) + l15;
    const int cf0 = (wv<<5) + l15;
    const int cf1 = cf0 + 16;
    const float bbr   = bb[cz] * KZ;
    const float b1r0  = b1[cf0]*K2,  b1r1  = b1[cf1]*K2;
    const float b2r0  = b2[cf0]*K2,  b2r1  = b2[cf1]*K2;
    const float batr0 = (ba[cf0]+btb[cf0])*K1, batr1 = (ba[cf1]+btb[cf1])*K1;
    const float bp1a  = bp1[cz];
    const float bp1k  = bp1a * K1;
    const float bp2r  = (wv < 4) ? bp2[cz] : 0.f;

    __syncthreads();

    const float* xrow = x + (size_t)(b0 + l15) * (T_*IND);
    f4 xq[4];
    #pragma unroll
    for (int q = 0; q < 4; ++q)
        xq[q] = *(const f4*)(xrow + ((q>>1)*32 + krow + (q&1)*4));

    half8 ha[8];
    {
        half8 hz;
        #pragma unroll
        for (int e = 0; e < 8; ++e) hz[e] = (_Float16)0.f;
        #pragma unroll
        for (int i = 0; i < 8; ++i) ha[i] = hz;
    }
    const f32x4 fz = {0.f, 0.f, 0.f, 0.f};
    float* const obase = out + (size_t)(b0 + (lg<<2)) * (T_*OUTD) + (wv<<4) + l15;

    #pragma unroll 1
    for (int t = 0; t < T_; ++t) {
        if (t > 0) {
            #pragma unroll
            for (int kk = 0; kk < 8; ++kk)
                ha[kk] = *(const half8*)&hbuf[(l15*LAT + kk*32 + krow) ^ ((l15&7)<<3)];
        }
        half8 xa0, xa1;
        #pragma unroll
        for (int e = 0; e < 4; ++e) {
            xa0[e]   = (_Float16)xq[0][e];
            xa0[e+4] = (_Float16)xq[1][e];
            xa1[e]   = (_Float16)xq[2][e];
            xa1[e+4] = (_Float16)xq[3][e];
        }
        {
            const int tn = (t < T_-1) ? (t+1) : t;
            const float* p = xrow + tn*IND + krow;
            #pragma unroll
            for (int q = 0; q < 4; ++q)
                xq[q] = *(const f4*)(p + (q>>1)*32 + (q&1)*4);
        }
        f32x4 az0 = MFMA16(xa0, WbB[0], fz);
        f32x4 az1 = MFMA16(xa1, WbB[1], fz);
        #pragma unroll
        for (int kk = 0; kk < 8; kk += 2) {
            az0 = MFMA16(ha[kk],   WbB[kk+2], az0);
            az1 = MFMA16(ha[kk+1], WbB[kk+3], az1);
        }
        const f32x4 az = az0 + az1;
        #pragma unroll
        for (int r = 0; r < 4; ++r) {
            const float E = ex2(__builtin_fmaf(az[r], KZ, bbr));
            const float z = __builtin_fmaf(-2.f, rcpf_(E + 1.f), 1.f);
            const int row = (lg<<2) + r;
            zbuf[(row*BBD + cz) ^ ((row&7)<<3)] = (_Float16)z;
        }
        if (t > 0) {
            f32x4 ap0 = fz, ap1 = fz;
            #pragma unroll
            for (int kk = 0; kk < 8; kk += 2) {
                ap0 = MFMA16(ha[kk],   *(const half8*)(wp1p +  kk   *512), ap0);
                ap1 = MFMA16(ha[kk+1], *(const half8*)(wp1p + (kk+1)*512), ap1);
            }
            const f32x4 ap = ap0 + ap1;
            #pragma unroll
            for (int r = 0; r < 4; ++r) {
                const float v  = ap[r] + bp1a;
                const float E  = ex2(__builtin_fmaf(ap[r], K1, bp1k));
                const float sg = rcpf_(E + 1.f);
                const float hd = __builtin_fmaf(-v, sg, v);
                const int row = (lg<<2) + r;
                dbuf[(row*HLF + cz) ^ ((row&7)<<3)] = (_Float16)hd;
            }
        }
        __syncthreads();

        half8 za[4];
        #pragma unroll
        for (int kk = 0; kk < 4; ++kk)
            za[kk] = *(const half8*)&zbuf[(l15*BBD + kk*32 + krow) ^ ((l15&7)<<3)];
        f32x4 af[6];
        #pragma unroll
        for (int i = 0; i < 6; ++i) af[i] = fz;
        #pragma unroll
        for (int kk = 0; kk < 4; ++kk) {
            #pragma unroll
            for (int i = 0; i < 6; ++i) af[i] = MFMA16(za[kk], WfB[i][kk], af[i]);
        }
        #pragma unroll
        for (int sub = 0; sub < 2; ++sub) {
            const float b1r  = sub ? b1r1  : b1r0;
            const float b2r  = sub ? b2r1  : b2r0;
            const float batr = sub ? batr1 : batr0;
            #pragma unroll
            for (int r = 0; r < 4; ++r) {
                const float E1 = ex2(__builtin_fmaf(af[0+sub][r], K2, b1r));
                const float E2 = ex2(__builtin_fmaf(af[2+sub][r], K2, b2r));
                const float E3 = ex2(__builtin_fmaf(af[4+sub][r], K1, batr));
                const float p1_ = E1 + 1.f;
                const float p2_ = E2 + 1.f;
                const float p3_ = E3 + 1.f;
                const float num = __builtin_fmaf(E3, p1_, p2_);
                const float hv  = __builtin_fmaf(-2.f*num, rcpf_(p1_*p2_*p3_), 1.f);
                const int row = (lg<<2) + r;
                hbuf[(row*LAT + (wv<<5) + (sub<<4) + l15) ^ ((row&7)<<3)] = (_Float16)hv;
            }
        }
        if (t > 0 && wv < 4) {
            f32x4 ao = fz;
            #pragma unroll
            for (int kk = 0; kk < 4; ++kk) {
                const half8 aa = *(const half8*)&dbuf[(l15*HLF + kk*32 + krow) ^ ((l15&7)<<3)];
                ao = MFMA16(aa, *(const half8*)(wp2p + kk*512), ao);
            }
            #pragma unroll
            for (int r = 0; r < 4; ++r)
                obase[(size_t)r*(T_*OUTD) + (size_t)(t-1)*OUTD] = ao[r] + bp2r;
        }
        __syncthreads();
    }
    {
        #pragma unroll
        for (int kk = 0; kk < 8; ++kk)
            ha[kk] = *(const half8*)&hbuf[(l15*LAT + kk*32 + krow) ^ ((l15&7)<<3)];
        f32x4 ap0 = fz, ap1 = fz;
        #pragma unroll
        for (int kk = 0; kk < 8; kk += 2) {
            ap0 = MFMA16(ha[kk],   *(const half8*)(wp1p +  kk   *512), ap0);
            ap1 = MFMA16(ha[kk+1], *(const half8*)(wp1p + (kk+1)*512), ap1);
        }
        const f32x4 ap = ap0 + ap1;
        #pragma unroll
        for (int r = 0; r < 4; ++r) {
            const float v  = ap[r] + bp1a;
            const float E  = ex2(__builtin_fmaf(ap[r], K1, bp1k));
            const float sg = rcpf_(E + 1.f);
            const float hd = __builtin_fmaf(-v, sg, v);
            const int row = (lg<<2) + r;
            dbuf[(row*HLF + cz) ^ ((row&7)<<3)] = (_Float16)hd;
        }
        __syncthreads();
        if (wv < 4) {
            f32x4 ao = fz;
            #pragma unroll
            for (int kk = 0; kk < 4; ++kk) {
                const half8 aa = *(const half8*)&dbuf[(l15*HLF + kk*32 + krow) ^ ((l15&7)<<3)];
                ao = MFMA16(aa, *(const half8*)(wp2p + kk*512), ao);
            }
            #pragma unroll
            for (int r = 0; r < 4; ++r)
                obase[(size_t)r*(T_*OUTD) + (size_t)(T_-1)*OUTD] = ao[r] + bp2r;
        }
    }
}

extern "C" void kernel_launch(void* const* d_in, const int* in_sizes, int n_in,
                              void* d_out, int out_size, void* d_ws, size_t ws_size,
                              hipStream_t stream) {
    (void)in_sizes; (void)n_in; (void)out_size;
    const float* x   = (const float*)d_in[0];
    const float* Wb  = (const float*)d_in[1];
    const float* bb  = (const float*)d_in[2];
    const float* W1  = (const float*)d_in[3];
    const float* b1  = (const float*)d_in[4];
    const float* W2  = (const float*)d_in[5];
    const float* b2  = (const float*)d_in[6];
    const float* Wa  = (const float*)d_in[7];
    const float* ba  = (const float*)d_in[8];
    const float* Wtb = (const float*)d_in[9];
    const float* btb = (const float*)d_in[10];
    const float* Wp1 = (const float*)d_in[11];
    const float* bp1 = (const float*)d_in[12];
    const float* Wp2 = (const float*)d_in[13];
    const float* bp2 = (const float*)d_in[14];

    const size_t seq_bytes = (size_t)256 * T_ * LAT * sizeof(_Float16);   // 67MB
    const size_t xh_bytes  = (size_t)256 * T_ * IND * sizeof(_Float16);   // 16.8MB

    if (ws_size >= seq_bytes + xh_bytes) {
        _Float16* seq = (_Float16*)d_ws;
        _Float16* xh  = (_Float16*)((char*)d_ws + seq_bytes);
        x2h<<<dim3(2048), dim3(256), 0, stream>>>(x, xh);
        cfc_scan6<true><<<dim3(64), dim3(512), 0, stream>>>(
            x, xh, Wb, bb, W1, b1, W2, b2, Wa, ba, Wtb, btb, seq);
        cfc_proj<<<dim3(2048), dim3(256), 0, stream>>>(
            seq, Wp1, bp1, Wp2, bp2, (float*)d_out);
    } else if (ws_size >= seq_bytes) {
        _Float16* seq = (_Float16*)d_ws;
        cfc_scan6<false><<<dim3(64), dim3(512), 0, stream>>>(
            x, nullptr, Wb, bb, W1, b1, W2, b2, Wa, ba, Wtb, btb, seq);
        cfc_proj<<<dim3(2048), dim3(256), 0, stream>>>(
            seq, Wp1, bp1, Wp2, bp2, (float*)d_out);
    } else {
        cfc_fused_fb<<<dim3(16), dim3(512), 0, stream>>>(
            x, Wb, bb, W1, b1, W2, b2, Wa, ba, Wtb, btb, Wp1, bp1, Wp2, bp2,
            (float*)d_out);
    }
}

// Round 12
// 499.094 us; speedup vs baseline: 2.1798x; 1.0605x over previous
//
#include <hip/hip_runtime.h>

// CfC, round 12: R11 (128 blocks x 2 rows, 8x dup, xz-hoist) with the
// hbuf pre-zero bug fixed: 2*HST fp16 = 576 elems = 288 DWORDS (was 144 ->
// row 1's h0 was garbage -> NaN).
//  MODE: 2 = xz path (ws>=135MB), 1 = XH fp16-x path (ws>=84MB),
//        0 = f32-x path (ws>=67MB); else fused fallback.

#define T_   512
#define IND  64
#define LAT  256
#define BBD  128
#define OUTD 64
#define HLF  128
#define HST  288
#define ZST  160

typedef _Float16 half8 __attribute__((ext_vector_type(8)));
typedef float    f32x4 __attribute__((ext_vector_type(4)));
typedef float    f4    __attribute__((ext_vector_type(4)));

#define MFMA16(a,b,c) __builtin_amdgcn_mfma_f32_16x16x32_f16((a),(b),(c),0,0,0)

__device__ __forceinline__ float ex2(float x)   { return __builtin_amdgcn_exp2f(x); }
__device__ __forceinline__ float rcpf_(float x) { return __builtin_amdgcn_rcpf(x); }
__device__ __forceinline__ void barrier_lds() {
    asm volatile("s_waitcnt lgkmcnt(0)\n\ts_barrier" ::: "memory");
}

// ====================== K0a: x -> fp16 pre-convert (MODE1) ==================
__global__ void __launch_bounds__(256) x2h(const float* __restrict__ x,
                                           _Float16* __restrict__ xh) {
    const size_t i = ((size_t)blockIdx.x * 256 + threadIdx.x) * 16;
    f4 a = *(const f4*)(x + i);
    f4 b = *(const f4*)(x + i + 4);
    f4 c = *(const f4*)(x + i + 8);
    f4 d = *(const f4*)(x + i + 12);
    half8 lo, hi;
    #pragma unroll
    for (int e = 0; e < 4; ++e) {
        lo[e] = (_Float16)a[e]; lo[e+4] = (_Float16)b[e];
        hi[e] = (_Float16)c[e]; hi[e+4] = (_Float16)d[e];
    }
    *(half8*)(xh + i)     = lo;
    *(half8*)(xh + i + 8) = hi;
}

// ====================== K0b: xz = x @ Wbx + bb (MODE2) ======================
// x as [131072][64] rows (row = b*T + t); xz f32 [131072][128].
__global__ void __launch_bounds__(256, 2) xzk(
    const float* __restrict__ x, const float* __restrict__ Wb,
    const float* __restrict__ bb, float* __restrict__ xz)
{
    const int tid  = threadIdx.x;
    const int wv   = tid >> 6;
    const int lane = tid & 63;
    const int l15  = lane & 15;
    const int lg   = lane >> 4;
    const int krow = lg << 3;
    const int m0   = (blockIdx.x * 4 + wv) << 4;   // 16-row tile

    // B-frags: Wb rows 0..63 (x part), 8 col tiles x 2 K-chunks
    half8 WB[8][2];
    #pragma unroll
    for (int tt = 0; tt < 8; ++tt) {
        const int col = (tt<<4) + l15;
        #pragma unroll
        for (int kk = 0; kk < 2; ++kk) {
            half8 v;
            #pragma unroll
            for (int e = 0; e < 8; ++e)
                v[e] = (_Float16)Wb[(kk*32 + krow + e)*BBD + col];
            WB[tt][kk] = v;
        }
    }
    float bbv[8];
    #pragma unroll
    for (int tt = 0; tt < 8; ++tt) bbv[tt] = bb[(tt<<4) + l15];

    // A-frags: x rows m0+l15 (f32 -> fp16)
    const float* xp = x + (size_t)(m0 + l15) * IND;
    half8 xa0, xa1;
    {
        f4 q0 = *(const f4*)(xp + krow);
        f4 q1 = *(const f4*)(xp + krow + 4);
        f4 q2 = *(const f4*)(xp + 32 + krow);
        f4 q3 = *(const f4*)(xp + 32 + krow + 4);
        #pragma unroll
        for (int e = 0; e < 4; ++e) {
            xa0[e] = (_Float16)q0[e]; xa0[e+4] = (_Float16)q1[e];
            xa1[e] = (_Float16)q2[e]; xa1[e+4] = (_Float16)q3[e];
        }
    }
    const f32x4 fz = {0.f, 0.f, 0.f, 0.f};
    #pragma unroll
    for (int tt = 0; tt < 8; ++tt) {
        f32x4 acc = MFMA16(xa0, WB[tt][0], fz);
        acc = MFMA16(xa1, WB[tt][1], acc);
        #pragma unroll
        for (int r = 0; r < 4; ++r)
            xz[(size_t)(m0 + (lg<<2) + r)*BBD + (tt<<4) + l15] = acc[r] + bbv[tt];
    }
}

// ============================ K1: recurrence scan ============================
// 128 blocks x 512 thr; block owns 2 batch rows (8x duplicated in M=16).
template<int MODE>   // 2 = xz, 1 = xh fp16, 0 = f32 x
__global__ void __launch_bounds__(512, 2) cfc_scan8(
    const float* __restrict__ x, const _Float16* __restrict__ xh,
    const float* __restrict__ xz,
    const float* __restrict__ Wb,  const float* __restrict__ bb,
    const float* __restrict__ W1,  const float* __restrict__ b1,
    const float* __restrict__ W2,  const float* __restrict__ b2,
    const float* __restrict__ Wa,  const float* __restrict__ ba,
    const float* __restrict__ Wtb, const float* __restrict__ btb,
    _Float16* __restrict__ seq)
{
    const int tid  = threadIdx.x;
    const int wv   = tid >> 6;
    const int lane = tid & 63;
    const int l15  = lane & 15;
    const int lg   = lane >> 4;     // 0..3
    const int krow = lg << 3;
    const int b0   = blockIdx.x << 1;     // 2 rows/block
    const int rl   = l15 & 1;             // duplicated data row for A-frags
    const int rB   = (lg >> 1) & 1;       // blend row this lane owns
    const int sB   = lg & 1;              // blend col sub-tile
    const int cB   = (wv<<5) + (sB<<4) + l15;   // blend col 0..255
    const int zr   = lg & 1;              // z row (lanes 0..31)
    const int cz   = (wv<<4) + l15;       // z col 0..127

    __shared__ __align__(16) _Float16 hbuf[2*HST];
    __shared__ __align__(16) _Float16 zbuf[2*ZST];

    const int NWB = (MODE == 2) ? 8 : 10;
    half8 WbB[10];
    {
        const int col = (wv<<4) + l15;
        const int kof = (MODE == 2) ? 64 : 0;   // xz mode: h-part only (rows 64+)
        for (int kk = 0; kk < NWB; ++kk) {
            half8 v;
            #pragma unroll
            for (int e = 0; e < 8; ++e)
                v[e] = (_Float16)Wb[(kof + kk*32 + krow + e)*BBD + col];
            WbB[kk] = v;
        }
    }
    half8 WfB[6][4];   // 0,1=W1 2,3=W2 4,5=Wa+Wtb ; 1.7159 folded
    #pragma unroll
    for (int t6 = 0; t6 < 6; ++t6) {
        const int m   = t6 >> 1;
        const int col = (wv<<5) + ((t6&1)<<4) + l15;
        const float* Wm = (m==0) ? W1 : ((m==1) ? W2 : Wa);
        #pragma unroll
        for (int kk = 0; kk < 4; ++kk) {
            half8 v;
            #pragma unroll
            for (int e = 0; e < 8; ++e) {
                const int k = kk*32 + krow + e;
                float f = Wm[k*LAT + col];
                if (m == 2) f += Wtb[k*LAT + col];
                v[e] = (_Float16)(1.7159f * f);
            }
            WfB[t6][kk] = v;
        }
    }

    const float K1 = 1.4426950408889634f;
    const float K2 = 2.8853900817779268f;
    const float KZ = 1.9216698144680396f;
    // blend biases at this lane's OWN col cB
    const float b1rs  = b1[cB]*K2;
    const float b2rs  = b2[cB]*K2;
    const float batrs = (ba[cB]+btb[cB])*K1;
    const float bbr   = (MODE == 2) ? 0.f : bb[cz]*KZ;   // folded into xz in MODE2

    // x source (per MODE)
    const float*    xrow  = x  + (size_t)(b0 + rl) * (T_*IND);
    const _Float16* xhrow = xh + (size_t)(b0 + rl) * (T_*IND);
    const float*    xzp   = xz + ((size_t)(b0 + zr) * T_) * BBD + cz;
    f4 xq[4];
    half8 xn0, xn1;
    float xzv = 0.f;
    if (MODE == 2) {
        xzv = xzp[0];
    } else if (MODE == 1) {
        xn0 = *(const half8*)(xhrow + krow);
        xn1 = *(const half8*)(xhrow + 32 + krow);
    } else {
        #pragma unroll
        for (int q = 0; q < 4; ++q)
            xq[q] = *(const f4*)(xrow + ((q>>1)*32 + krow + (q&1)*4));
    }

    // pre-zero hbuf (h0 = 0): 2*HST fp16 = 576 elems = 288 DWORDS
    if (tid < 288) ((unsigned int*)hbuf)[tid] = 0u;
    barrier_lds();

    const f32x4 fz = {0.f, 0.f, 0.f, 0.f};
    _Float16* const sq = seq + (size_t)(b0 + rB) * (T_*LAT) + cB;

    #pragma unroll 1
    for (int t = 0; t < T_; ++t) {
        // ============================ PHASE A ============================
        half8 ha[8];
        #pragma unroll
        for (int kk = 0; kk < 8; ++kk)
            ha[kk] = *(const half8*)&hbuf[rl*HST + kk*32 + krow];

        f32x4 az;
        if (MODE == 2) {
            // GEMM_h (h only, 8 chunks, 2 chains)
            f32x4 az0 = MFMA16(ha[0], WbB[0], fz);
            f32x4 az1 = MFMA16(ha[1], WbB[1], fz);
            #pragma unroll
            for (int kk = 2; kk < 8; kk += 2) {
                az0 = MFMA16(ha[kk],   WbB[kk],   az0);
                az1 = MFMA16(ha[kk+1], WbB[kk+1], az1);
            }
            az = az0 + az1;
        } else {
            half8 xa0, xa1;
            if (MODE == 1) {
                xa0 = xn0; xa1 = xn1;
                const int tn = (t < T_-1) ? (t+1) : t;
                xn0 = *(const half8*)(xhrow + tn*IND + krow);
                xn1 = *(const half8*)(xhrow + tn*IND + 32 + krow);
            } else {
                #pragma unroll
                for (int e = 0; e < 4; ++e) {
                    xa0[e]   = (_Float16)xq[0][e];
                    xa0[e+4] = (_Float16)xq[1][e];
                    xa1[e]   = (_Float16)xq[2][e];
                    xa1[e+4] = (_Float16)xq[3][e];
                }
                const int tn = (t < T_-1) ? (t+1) : t;
                const float* p = xrow + tn*IND + krow;
                #pragma unroll
                for (int q = 0; q < 4; ++q)
                    xq[q] = *(const f4*)(p + (q>>1)*32 + (q&1)*4);
            }
            f32x4 azx = MFMA16(xa0, WbB[0], fz);
            azx = MFMA16(xa1, WbB[1], azx);
            f32x4 az0 = MFMA16(ha[0], WbB[2], fz);
            f32x4 az1 = MFMA16(ha[1], WbB[3], fz);
            #pragma unroll
            for (int kk = 2; kk < 8; kk += 2) {
                az0 = MFMA16(ha[kk],   WbB[kk+2], az0);
                az1 = MFMA16(ha[kk+1], WbB[kk+3], az1);
            }
            az = (azx + az0) + az1;
        }

        // z slot: all lanes compute, lanes 0..31 store (row zr, col cz)
        {
            const float vzr = zr ? az[1] : az[0];   // acc elem r -> data row r&1
            float v;
            if (MODE == 2) {
                v = (vzr + xzv) * KZ;
                const int tn = (t < T_-1) ? (t+1) : t;
                xzv = xzp[(size_t)tn * BBD];        // prefetch next step
            } else {
                v = __builtin_fmaf(vzr, KZ, bbr);
            }
            const float E  = ex2(v);
            const float zv = __builtin_fmaf(-2.f, rcpf_(E + 1.f), 1.f);
            if (lane < 32) zbuf[zr*ZST + cz] = (_Float16)zv;
        }
        barrier_lds();   // bar 1: zbuf ready

        // ============================ PHASE B ============================
        half8 za[4];
        #pragma unroll
        for (int kk = 0; kk < 4; ++kk)
            za[kk] = *(const half8*)&zbuf[rl*ZST + kk*32 + krow];

        f32x4 af0 = fz, af2 = fz, af4 = fz;
        #pragma unroll
        for (int kk = 0; kk < 4; ++kk) {
            af0 = MFMA16(za[kk], WfB[0][kk], af0);
            af2 = MFMA16(za[kk], WfB[2][kk], af2);
            af4 = MFMA16(za[kk], WfB[4][kk], af4);
        }
        f32x4 af1 = fz, af3 = fz, af5 = fz;
        #pragma unroll
        for (int kk = 0; kk < 4; ++kk) {
            af1 = MFMA16(za[kk], WfB[1][kk], af1);
            af3 = MFMA16(za[kk], WfB[3][kk], af3);
            af5 = MFMA16(za[kk], WfB[5][kk], af5);
        }

        // blend slot: ONE value per lane (row rB, col cB)
        {
            float t0, t1;
            t0 = sB ? af1[0] : af0[0];  t1 = sB ? af1[1] : af0[1];
            const float a1v = rB ? t1 : t0;
            t0 = sB ? af3[0] : af2[0];  t1 = sB ? af3[1] : af2[1];
            const float a2v = rB ? t1 : t0;
            t0 = sB ? af5[0] : af4[0];  t1 = sB ? af5[1] : af4[1];
            const float a3v = rB ? t1 : t0;

            const float E1 = ex2(__builtin_fmaf(a1v, K2, b1rs));
            const float E2 = ex2(__builtin_fmaf(a2v, K2, b2rs));
            const float E3 = ex2(__builtin_fmaf(a3v, K1, batrs));
            const float p1_ = E1 + 1.f;
            const float p2_ = E2 + 1.f;
            const float p3_ = E3 + 1.f;
            const float num = __builtin_fmaf(E3, p1_, p2_);
            const float hv  = __builtin_fmaf(-2.f*num, rcpf_(p1_*p2_*p3_), 1.f);
            const _Float16 hh = (_Float16)hv;
            hbuf[rB*HST + cB] = hh;
            sq[(size_t)t * LAT] = hh;
        }
        barrier_lds();   // bar 2: hbuf ready for t+1
    }
}

// ============================ K2: projection =================================
__global__ void __launch_bounds__(256, 2) cfc_proj(
    const _Float16* __restrict__ seq,
    const float* __restrict__ Wp1, const float* __restrict__ bp1,
    const float* __restrict__ Wp2, const float* __restrict__ bp2,
    float* __restrict__ out)
{
    const int tid  = threadIdx.x;
    const int wv   = tid >> 6;      // 0..3
    const int lane = tid & 63;
    const int l15  = lane & 15;
    const int lg   = lane >> 4;
    const int krow = lg << 3;

    __shared__ __align__(16) _Float16 wp1l[64*512];      // 64KB
    __shared__ __align__(16) _Float16 wp2l[16*512];      // 16KB
    __shared__ __align__(16) _Float16 dbuf[4][16*HLF];   // 16KB

    #pragma unroll
    for (int f = 0; f < 16; ++f) {
        const int g = wv*16 + f, tt = g >> 3, kk = g & 7;
        half8 v;
        #pragma unroll
        for (int e = 0; e < 8; ++e)
            v[e] = (_Float16)Wp1[(kk*32 + krow + e)*HLF + (tt<<4) + l15];
        *(half8*)&wp1l[g*512 + (lane<<3)] = v;
    }
    #pragma unroll
    for (int f = 0; f < 4; ++f) {
        const int g = wv*4 + f, tt = g >> 2, kk = g & 3;
        half8 v;
        #pragma unroll
        for (int e = 0; e < 8; ++e)
            v[e] = (_Float16)Wp2[(kk*32 + krow + e)*OUTD + (tt<<4) + l15];
        *(half8*)&wp2l[g*512 + (lane<<3)] = v;
    }

    const float K1 = 1.4426950408889634f;
    float bp1v[8], bp1kv[8];
    #pragma unroll
    for (int tt = 0; tt < 8; ++tt) {
        bp1v[tt]  = bp1[(tt<<4) + l15];
        bp1kv[tt] = bp1v[tt] * K1;
    }
    float bp2v[4];
    #pragma unroll
    for (int tt = 0; tt < 4; ++tt) bp2v[tt] = bp2[(tt<<4) + l15];

    __syncthreads();

    const int m0 = (blockIdx.x*4 + wv) << 4;
    const f32x4 fz = {0.f, 0.f, 0.f, 0.f};

    half8 ha[8];
    {
        const _Float16* ap = seq + (size_t)(m0 + l15)*LAT + krow;
        #pragma unroll
        for (int kk = 0; kk < 8; ++kk)
            ha[kk] = *(const half8*)(ap + kk*32);
    }

    #pragma unroll
    for (int tt = 0; tt < 8; ++tt) {
        f32x4 a0 = fz, a1 = fz;
        #pragma unroll
        for (int kk = 0; kk < 8; kk += 2) {
            a0 = MFMA16(ha[kk],   *(const half8*)&wp1l[((tt<<3)+kk  )*512 + (lane<<3)], a0);
            a1 = MFMA16(ha[kk+1], *(const half8*)&wp1l[((tt<<3)+kk+1)*512 + (lane<<3)], a1);
        }
        const f32x4 ap = a0 + a1;
        #pragma unroll
        for (int r = 0; r < 4; ++r) {
            const float v  = ap[r] + bp1v[tt];
            const float E  = ex2(__builtin_fmaf(ap[r], K1, bp1kv[tt]));
            const float sg = rcpf_(E + 1.f);
            const float hd = __builtin_fmaf(-v, sg, v);
            const int row = (lg<<2) + r;
            dbuf[wv][(row*HLF + (tt<<4) + l15) ^ ((row&7)<<3)] = (_Float16)hd;
        }
    }

    half8 pa[4];
    #pragma unroll
    for (int kk = 0; kk < 4; ++kk)
        pa[kk] = *(const half8*)&dbuf[wv][(l15*HLF + kk*32 + krow) ^ ((l15&7)<<3)];
    #pragma unroll
    for (int tt = 0; tt < 4; ++tt) {
        f32x4 ao = fz;
        #pragma unroll
        for (int kk = 0; kk < 4; ++kk)
            ao = MFMA16(pa[kk], *(const half8*)&wp2l[((tt<<2)+kk)*512 + (lane<<3)], ao);
        #pragma unroll
        for (int r = 0; r < 4; ++r)
            out[(size_t)(m0 + (lg<<2) + r)*OUTD + (tt<<4) + l15] = ao[r] + bp2v[tt];
    }
}

// ==================== fallback: R3 fused kernel (ws too small) ===============
__global__ void __launch_bounds__(512, 2) cfc_fused_fb(
    const float* __restrict__ x,
    const float* __restrict__ Wb,  const float* __restrict__ bb,
    const float* __restrict__ W1,  const float* __restrict__ b1,
    const float* __restrict__ W2,  const float* __restrict__ b2,
    const float* __restrict__ Wa,  const float* __restrict__ ba,
    const float* __restrict__ Wtb, const float* __restrict__ btb,
    const float* __restrict__ Wp1, const float* __restrict__ bp1,
    const float* __restrict__ Wp2, const float* __restrict__ bp2,
    float* __restrict__ out)
{
    const int tid  = threadIdx.x;
    const int wv   = tid >> 6;
    const int lane = tid & 63;
    const int l15  = lane & 15;
    const int lg   = lane >> 4;
    const int krow = lg << 3;
    const int b0   = blockIdx.x << 4;

    __shared__ __align__(16) _Float16 hbuf[16*LAT];
    __shared__ __align__(16) _Float16 zbuf[16*BBD];
    __shared__ __align__(16) _Float16 dbuf[16*HLF];
    __shared__ __align__(16) _Float16 wp1l[64*512];
    __shared__ __align__(16) _Float16 wp2l[16*512];

    half8 WbB[10];
    {
        const int col = (wv<<4) + l15;
        #pragma unroll
        for (int kk = 0; kk < 10; ++kk) {
            half8 v;
            #pragma unroll
            for (int e = 0; e < 8; ++e)
                v[e] = (_Float16)Wb[(kk*32 + krow + e)*BBD + col];
            WbB[kk] = v;
        }
    }
    half8 WfB[6][4];
    #pragma unroll
    for (int t6 = 0; t6 < 6; ++t6) {
        const int m   = t6 >> 1;
        const int col = (wv<<5) + ((t6&1)<<4) + l15;
        const float* Wm = (m==0) ? W1 : ((m==1) ? W2 : Wa);
        #pragma unroll
        for (int kk = 0; kk < 4; ++kk) {
            half8 v;
            #pragma unroll
            for (int e = 0; e < 8; ++e) {
                const int k = kk*32 + krow + e;
                float f = Wm[k*LAT + col];
                if (m == 2) f += Wtb[k*LAT + col];
                v[e] = (_Float16)(1.7159f * f);
            }
            WfB[t6][kk] = v;
        }
    }
    {
        const int col = (wv<<4) + l15;
        #pragma unroll
        for (int kk = 0; kk < 8; ++kk) {
            half8 v;
            #pragma unroll
            for (int e = 0; e < 8; ++e)
                v[e] = (_Float16)Wp1[(kk*32 + krow + e)*HLF + col];
            *(half8*)&wp1l[((wv<<3) + kk)*512 + (lane<<3)] = v;
        }
        if (wv < 4) {
            #pragma unroll
            for (int kk = 0; kk < 4; ++kk) {
                half8 v;
                #pragma unroll
                for (int e = 0; e < 8; ++e)
                    v[e] = (_Float16)Wp2[(kk*32 + krow + e)*OUTD + col];
                *(half8*)&wp2l[((wv<<2) + kk)*512 + (lane<<3)] = v;
            }
        }
    }
    const _Float16* const wp1p = &wp1l[(wv<<3)*512 + (lane<<3)];
    const _Float16* const wp2p = &wp2l[(wv<<2)*512 + (lane<<3)];

    const float K1 = 1.4426950408889634f;
    const float K2 = 2.8853900817779268f;
    const float KZ = 1.9216698144680396f;
    const int cz  = (wv<<4) + l15;
    const int cf0 = (wv<<5) + l15;
    const int cf1 = cf0 + 16;
    const float bbr   = bb[cz] * KZ;
    const float b1r0  = b1[cf0]*K2,  b1r1  = b1[cf1]*K2;
    const float b2r0  = b2[cf0]*K2,  b2r1  = b2[cf1]*K2;
    const float batr0 = (ba[cf0]+btb[cf0])*K1, batr1 = (ba[cf1]+btb[cf1])*K1;
    const float bp1a  = bp1[cz];
    const float bp1k  = bp1a * K1;
    const float bp2r  = (wv < 4) ? bp2[cz] : 0.f;

    __syncthreads();

    const float* xrow = x + (size_t)(b0 + l15) * (T_*IND);
    f4 xq[4];
    #pragma unroll
    for (int q = 0; q < 4; ++q)
        xq[q] = *(const f4*)(xrow + ((q>>1)*32 + krow + (q&1)*4));

    half8 ha[8];
    {
        half8 hz;
        #pragma unroll
        for (int e = 0; e < 8; ++e) hz[e] = (_Float16)0.f;
        #pragma unroll
        for (int i = 0; i < 8; ++i) ha[i] = hz;
    }
    const f32x4 fz = {0.f, 0.f, 0.f, 0.f};
    float* const obase = out + (size_t)(b0 + (lg<<2)) * (T_*OUTD) + (wv<<4) + l15;

    #pragma unroll 1
    for (int t = 0; t < T_; ++t) {
        if (t > 0) {
            #pragma unroll
            for (int kk = 0; kk < 8; ++kk)
                ha[kk] = *(const half8*)&hbuf[(l15*LAT + kk*32 + krow) ^ ((l15&7)<<3)];
        }
        half8 xa0, xa1;
        #pragma unroll
        for (int e = 0; e < 4; ++e) {
            xa0[e]   = (_Float16)xq[0][e];
            xa0[e+4] = (_Float16)xq[1][e];
            xa1[e]   = (_Float16)xq[2][e];
            xa1[e+4] = (_Float16)xq[3][e];
        }
        {
            const int tn = (t < T_-1) ? (t+1) : t;
            const float* p = xrow + tn*IND + krow;
            #pragma unroll
            for (int q = 0; q < 4; ++q)
                xq[q] = *(const f4*)(p + (q>>1)*32 + (q&1)*4);
        }
        f32x4 az0 = MFMA16(xa0, WbB[0], fz);
        f32x4 az1 = MFMA16(xa1, WbB[1], fz);
        #pragma unroll
        for (int kk = 0; kk < 8; kk += 2) {
            az0 = MFMA16(ha[kk],   WbB[kk+2], az0);
            az1 = MFMA16(ha[kk+1], WbB[kk+3], az1);
        }
        const f32x4 az = az0 + az1;
        #pragma unroll
        for (int r = 0; r < 4; ++r) {
            const float E = ex2(__builtin_fmaf(az[r], KZ, bbr));
            const float z = __builtin_fmaf(-2.f, rcpf_(E + 1.f), 1.f);
            const int row = (lg<<2) + r;
            zbuf[(row*BBD + cz) ^ ((row&7)<<3)] = (_Float16)z;
        }
        if (t > 0) {
            f32x4 ap0 = fz, ap1 = fz;
            #pragma unroll
            for (int kk = 0; kk < 8; kk += 2) {
                ap0 = MFMA16(ha[kk],   *(const half8*)(wp1p +  kk   *512), ap0);
                ap1 = MFMA16(ha[kk+1], *(const half8*)(wp1p + (kk+1)*512), ap1);
            }
            const f32x4 ap = ap0 + ap1;
            #pragma unroll
            for (int r = 0; r < 4; ++r) {
                const float v  = ap[r] + bp1a;
                const float E  = ex2(__builtin_fmaf(ap[r], K1, bp1k));
                const float sg = rcpf_(E + 1.f);
                const float hd = __builtin_fmaf(-v, sg, v);
                const int row = (lg<<2) + r;
                dbuf[(row*HLF + cz) ^ ((row&7)<<3)] = (_Float16)hd;
            }
        }
        __syncthreads();

        half8 za[4];
        #pragma unroll
        for (int kk = 0; kk < 4; ++kk)
            za[kk] = *(const half8*)&zbuf[(l15*BBD + kk*32 + krow) ^ ((l15&7)<<3)];
        f32x4 af[6];
        #pragma unroll
        for (int i = 0; i < 6; ++i) af[i] = fz;
        #pragma unroll
        for (int kk = 0; kk < 4; ++kk) {
            #pragma unroll
            for (int i = 0; i < 6; ++i) af[i] = MFMA16(za[kk], WfB[i][kk], af[i]);
        }
        #pragma unroll
        for (int sub = 0; sub < 2; ++sub) {
            const float b1r  = sub ? b1r1  : b1r0;
            const float b2r  = sub ? b2r1  : b2r0;
            const float batr = sub ? batr1 : batr0;
            #pragma unroll
            for (int r = 0; r < 4; ++r) {
                const float E1 = ex2(__builtin_fmaf(af[0+sub][r], K2, b1r));
                const float E2 = ex2(__builtin_fmaf(af[2+sub][r], K2, b2r));
                const float E3 = ex2(__builtin_fmaf(af[4+sub][r], K1, batr));
                const float p1_ = E1 + 1.f;
                const float p2_ = E2 + 1.f;
                const float p3_ = E3 + 1.f;
                const float num = __builtin_fmaf(E3, p1_, p2_);
                const float hv  = __builtin_fmaf(-2.f*num, rcpf_(p1_*p2_*p3_), 1.f);
                const int row = (lg<<2) + r;
                hbuf[(row*LAT + (wv<<5) + (sub<<4) + l15) ^ ((row&7)<<3)] = (_Float16)hv;
            }
        }
        if (t > 0 && wv < 4) {
            f32x4 ao = fz;
            #pragma unroll
            for (int kk = 0; kk < 4; ++kk) {
                const half8 aa = *(const half8*)&dbuf[(l15*HLF + kk*32 + krow) ^ ((l15&7)<<3)];
                ao = MFMA16(aa, *(const half8*)(wp2p + kk*512), ao);
            }
            #pragma unroll
            for (int r = 0; r < 4; ++r)
                obase[(size_t)r*(T_*OUTD) + (size_t)(t-1)*OUTD] = ao[r] + bp2r;
        }
        __syncthreads();
    }
    {
        #pragma unroll
        for (int kk = 0; kk < 8; ++kk)
            ha[kk] = *(const half8*)&hbuf[(l15*LAT + kk*32 + krow) ^ ((l15&7)<<3)];
        f32x4 ap0 = fz, ap1 = fz;
        #pragma unroll
        for (int kk = 0; kk < 8; kk += 2) {
            ap0 = MFMA16(ha[kk],   *(const half8*)(wp1p +  kk   *512), ap0);
            ap1 = MFMA16(ha[kk+1], *(const half8*)(wp1p + (kk+1)*512), ap1);
        }
        const f32x4 ap = ap0 + ap1;
        #pragma unroll
        for (int r = 0; r < 4; ++r) {
            const float v  = ap[r] + bp1a;
            const float E  = ex2(__builtin_fmaf(ap[r], K1, bp1k));
            const float sg = rcpf_(E + 1.f);
            const float hd = __builtin_fmaf(-v, sg, v);
            const int row = (lg<<2) + r;
            dbuf[(row*HLF + cz) ^ ((row&7)<<3)] = (_Float16)hd;
        }
        __syncthreads();
        if (wv < 4) {
            f32x4 ao = fz;
            #pragma unroll
            for (int kk = 0; kk < 4; ++kk) {
                const half8 aa = *(const half8*)&dbuf[(l15*HLF + kk*32 + krow) ^ ((l15&7)<<3)];
                ao = MFMA16(aa, *(const half8*)(wp2p + kk*512), ao);
            }
            #pragma unroll
            for (int r = 0; r < 4; ++r)
                obase[(size_t)r*(T_*OUTD) + (size_t)(T_-1)*OUTD] = ao[r] + bp2r;
        }
    }
}

extern "C" void kernel_launch(void* const* d_in, const int* in_sizes, int n_in,
                              void* d_out, int out_size, void* d_ws, size_t ws_size,
                              hipStream_t stream) {
    (void)in_sizes; (void)n_in; (void)out_size;
    const float* x   = (const float*)d_in[0];
    const float* Wb  = (const float*)d_in[1];
    const float* bb  = (const float*)d_in[2];
    const float* W1  = (const float*)d_in[3];
    const float* b1  = (const float*)d_in[4];
    const float* W2  = (const float*)d_in[5];
    const float* b2  = (const float*)d_in[6];
    const float* Wa  = (const float*)d_in[7];
    const float* ba  = (const float*)d_in[8];
    const float* Wtb = (const float*)d_in[9];
    const float* btb = (const float*)d_in[10];
    const float* Wp1 = (const float*)d_in[11];
    const float* bp1 = (const float*)d_in[12];
    const float* Wp2 = (const float*)d_in[13];
    const float* bp2 = (const float*)d_in[14];

    const size_t seq_bytes = (size_t)256 * T_ * LAT * sizeof(_Float16);   // 67.1MB
    const size_t xz_bytes  = (size_t)256 * T_ * BBD * sizeof(float);      // 67.1MB
    const size_t xh_bytes  = (size_t)256 * T_ * IND * sizeof(_Float16);   // 16.8MB

    _Float16* seq = (_Float16*)d_ws;
    if (ws_size >= seq_bytes + xz_bytes) {
        float* xzbuf = (float*)((char*)d_ws + seq_bytes);
        xzk<<<dim3(2048), dim3(256), 0, stream>>>(x, Wb, bb, xzbuf);
        cfc_scan8<2><<<dim3(128), dim3(512), 0, stream>>>(
            x, nullptr, xzbuf, Wb, bb, W1, b1, W2, b2, Wa, ba, Wtb, btb, seq);
        cfc_proj<<<dim3(2048), dim3(256), 0, stream>>>(
            seq, Wp1, bp1, Wp2, bp2, (float*)d_out);
    } else if (ws_size >= seq_bytes + xh_bytes) {
        _Float16* xh = (_Float16*)((char*)d_ws + seq_bytes);
        x2h<<<dim3(2048), dim3(256), 0, stream>>>(x, xh);
        cfc_scan8<1><<<dim3(128), dim3(512), 0, stream>>>(
            x, xh, nullptr, Wb, bb, W1, b1, W2, b2, Wa, ba, Wtb, btb, seq);
        cfc_proj<<<dim3(2048), dim3(256), 0, stream>>>(
            seq, Wp1, bp1, Wp2, bp2, (float*)d_out);
    } else if (ws_size >= seq_bytes) {
        cfc_scan8<0><<<dim3(128), dim3(512), 0, stream>>>(
            x, nullptr, nullptr, Wb, bb, W1, b1, W2, b2, Wa, ba, Wtb, btb, seq);
        cfc_proj<<<dim3(2048), dim3(256), 0, stream>>>(
            seq, Wp1, bp1, Wp2, bp2, (float*)d_out);
    } else {
        cfc_fused_fb<<<dim3(16), dim3(512), 0, stream>>>(
            x, Wb, bb, W1, b1, W2, b2, Wa, ba, Wtb, btb, Wp1, bp1, Wp2, bp2,
            (float*)d_out);
    }
}